// Round 6
// baseline (321.446 us; speedup 1.0000x reference)
//
#include <hip/hip_runtime.h>

// ---------------------------------------------------------------------------
// GNN_6305011991202: 2-layer GraphSAGE (mean aggr) + linear head. fp32 I/O.
//   h1 = relu(mean1 @ W1_l^T + b1_l + x  @ W1_r^T)
//   h2 = relu(mean2 @ W2_l^T + b2_l + h1 @ W2_r^T)
//   out = h2 @ W3^T + b3          (out: [50000, 64] fp32)
// R6: fused per-layer kernel (gather-mean -> LDS -> dual MFMA GEMM), 8
// launches total; mean buffer eliminated (no global round-trip).
// ---------------------------------------------------------------------------

typedef __bf16 bf16x8 __attribute__((ext_vector_type(8)));
typedef float floatx4 __attribute__((ext_vector_type(4)));

__device__ __forceinline__ float bf2f(unsigned int u) {
    union { unsigned int i; float f; } c;
    c.i = u << 16;
    return c.f;
}
__device__ __forceinline__ unsigned short f2bf(float f) {
    union { float f; unsigned int i; } c;
    c.f = f;
    unsigned int i = c.i;
    unsigned int r = (i + 0x7fffu + ((i >> 16) & 1u)) >> 16;  // RNE
    return (unsigned short)r;
}
__device__ __forceinline__ ushort4 cvt4(float4 v) {
    ushort4 o;
    o.x = f2bf(v.x); o.y = f2bf(v.y); o.z = f2bf(v.z); o.w = f2bf(v.w);
    return o;
}

// ---------------------------------------------------------------------------
// Fused prologue: convert 5 weight mats (contiguous dst), convert x, zero deg.
#define WSEG 18432
__global__ __launch_bounds__(256) void prologue_kernel(
    const float* __restrict__ W1l, const float* __restrict__ W1r,
    const float* __restrict__ W2l, const float* __restrict__ W2r,
    const float* __restrict__ W3,  const float* __restrict__ x,
    unsigned short* __restrict__ wb,   // 5 weight dsts contiguous
    unsigned short* __restrict__ xb,
    int* __restrict__ deg, int NX4, int ND4)
{
    int i = blockIdx.x * 256 + threadIdx.x;
    if (i < WSEG) {
        const float* s; int l;
        if (i < 8192)       { if (i < 4096) { s = W1l; l = i; }
                              else          { s = W1r; l = i - 4096; } }
        else if (i < 16384) { if (i < 12288){ s = W2l; l = i - 8192; }
                              else          { s = W2r; l = i - 12288; } }
        else                { s = W3; l = i - 16384; }
        ((ushort4*)wb)[i] = cvt4(((const float4*)s)[l]);
        return;
    }
    int j = i - WSEG;
    if (j < NX4) { ((ushort4*)xb)[j] = cvt4(((const float4*)x)[j]); return; }
    int k = j - NX4;
    if (k < ND4) ((int4*)deg)[k] = make_int4(0, 0, 0, 0);
}

// ---------------------------------------------------------------------------
// CSR build step 1: degree histogram over dst
__global__ __launch_bounds__(256) void hist_kernel(const int* __restrict__ dst,
                                                   int* __restrict__ deg, int E) {
    int e = blockIdx.x * 256 + threadIdx.x;
    if (e < E) atomicAdd(deg + dst[e], 1);
}

// CSR scan A: per-block sums (1024 elems/block)
__global__ __launch_bounds__(256) void scan_partial_kernel(
    const int* __restrict__ deg, int* __restrict__ partials, int N)
{
    __shared__ int ws[4];
    const int t = threadIdx.x, lane = t & 63, wave = t >> 6;
    const int i4 = blockIdx.x * 256 + t;
    const int n4 = (N + 3) / 4;
    int s = 0;
    if (i4 < n4) {
        int b = i4 * 4;
        if (b + 3 < N) {
            int4 v = ((const int4*)deg)[i4];
            s = v.x + v.y + v.z + v.w;
        } else {
            for (int q = 0; q < 4 && b + q < N; ++q) s += deg[b + q];
        }
    }
#pragma unroll
    for (int off = 32; off > 0; off >>= 1) s += __shfl_xor(s, off, 64);
    if (lane == 0) ws[wave] = s;
    __syncthreads();
    if (t == 0) partials[blockIdx.x] = ws[0] + ws[1] + ws[2] + ws[3];
}

// CSR scan B+C merged: each block redundantly reduces partials[< blockIdx]
// (P <= 64), re-scans its 1024 elems, writes rowptr & cursor.
__global__ __launch_bounds__(256) void scan_apply_kernel(
    const int* __restrict__ deg, const int* __restrict__ partials,
    int* __restrict__ rowptr, int* __restrict__ cursor, int N, int P)
{
    __shared__ int woff[4];
    __shared__ int s_base;
    const int t = threadIdx.x, lane = t & 63, wave = t >> 6;
    const int i4 = blockIdx.x * 256 + t;
    const int n4 = (N + 3) / 4;
    const int b = i4 * 4;

    if (wave == 0) {          // exclusive sum of block partials below us
        int v = (lane < P && lane < (int)blockIdx.x) ? partials[lane] : 0;
#pragma unroll
        for (int off = 32; off > 0; off >>= 1) v += __shfl_xor(v, off, 64);
        if (lane == 0) s_base = v;
    }

    int4 v = make_int4(0, 0, 0, 0);
    if (i4 < n4) {
        if (b + 3 < N) v = ((const int4*)deg)[i4];
        else {
            if (b + 0 < N) v.x = deg[b + 0];
            if (b + 1 < N) v.y = deg[b + 1];
            if (b + 2 < N) v.z = deg[b + 2];
        }
    }
    const int p1 = v.x, p2 = v.x + v.y, p3 = v.x + v.y + v.z;
    const int tsum = p3 + v.w;
    int incl = tsum;
#pragma unroll
    for (int off = 1; off < 64; off <<= 1) {
        int tt = __shfl_up(incl, off, 64);
        if (lane >= off) incl += tt;
    }
    const int texcl = incl - tsum;
    if (lane == 63) woff[wave] = incl;
    __syncthreads();
    int wo = 0;
#pragma unroll
    for (int w = 0; w < 4; ++w) if (w < wave) wo += woff[w];
    const int e = s_base + wo + texcl;
    if (blockIdx.x == 0 && t == 0) rowptr[0] = 0;
    if (b + 3 < N) {
        ((int4*)cursor)[i4] = make_int4(e, e + p1, e + p2, e + p3);
        rowptr[b + 1] = e + p1;
        rowptr[b + 2] = e + p2;
        rowptr[b + 3] = e + p3;
        rowptr[b + 4] = e + tsum;
    } else if (b < N) {
        if (b + 0 < N) { cursor[b + 0] = e;      rowptr[b + 1] = e + p1; }
        if (b + 1 < N) { cursor[b + 1] = e + p1; rowptr[b + 2] = e + p2; }
        if (b + 2 < N) { cursor[b + 2] = e + p2; rowptr[b + 3] = e + p3; }
    }
}

// CSR build: scatter src ids into neighbor lists
__global__ __launch_bounds__(256) void fill_kernel(const int* __restrict__ src,
                                                   const int* __restrict__ dst,
                                                   int* __restrict__ cursor,
                                                   int* __restrict__ csr, int E) {
    int e = blockIdx.x * 256 + threadIdx.x;
    if (e >= E) return;
    int pos = atomicAdd(cursor + dst[e], 1);
    csr[pos] = src[e];
}

// ---------------------------------------------------------------------------
// Fused SAGE layer: out = relu( mean(feat,nbrs) @ Wl^T + bias + feat @ Wr^T )
// Block = 4 waves = 64 nodes (4 MFMA row-tiles of 16).
// Phase 1: per wave, gather-mean its 16 nodes (lane = 2 feature cols, one
//   coalesced 256B row read per neighbor, 4-deep ILP) -> bf16 into LDS.
// Phase 2: dual-MFMA GEMM, A-fragments from LDS, self-fragments from global.
// LDS row stride 136 shorts (+8 pad): phase-1 dword writes and phase-2
// ds_read_b128 both land 2 lanes/bank == conflict-free (m136).
// mfma_f32_16x16x32_bf16 layout (HW-verified m89/m91):
//   A/B elem [m = lane&15][k = (lane>>4)*8 + j]; C/D [row=(lane>>4)*4+reg][col=lane&15].
__global__ __launch_bounds__(256) void sage_layer_kernel(
    const unsigned short* __restrict__ feat,   // [N,128] bf16 (gather + self)
    const int* __restrict__ rowptr, const int* __restrict__ csr,
    const unsigned short* __restrict__ Wl,
    const unsigned short* __restrict__ Wr,
    const float* __restrict__ bias,
    unsigned short* __restrict__ out,          // [N,128] bf16
    int N)
{
    __shared__ unsigned short smean[4][16][136];
    const int wave = threadIdx.x >> 6;
    const int lane = threadIdx.x & 63;
    const int r0 = (blockIdx.x * 4 + wave) * 16;

    // ---- phase 1: gather means for this wave's 16 nodes ----
    if (r0 < N) {
        const unsigned short* fp = feat + lane * 2;
        for (int mi = 0; mi < 16; ++mi) {
            const int n = r0 + mi;
            const int beg = rowptr[n], end = rowptr[n + 1];
            float acc0 = 0.f, acc1 = 0.f;
            for (int j0 = beg; j0 < end; j0 += 64) {
                int cnt = min(64, end - j0);
                int idx = (lane < cnt) ? csr[j0 + lane] : 0;
                int j = 0;
                for (; j + 4 <= cnt; j += 4) {
                    int s0 = __shfl(idx, j + 0, 64);
                    int s1 = __shfl(idx, j + 1, 64);
                    int s2 = __shfl(idx, j + 2, 64);
                    int s3 = __shfl(idx, j + 3, 64);
                    unsigned int p0 = *(const unsigned int*)(fp + (size_t)s0 * 128);
                    unsigned int p1 = *(const unsigned int*)(fp + (size_t)s1 * 128);
                    unsigned int p2 = *(const unsigned int*)(fp + (size_t)s2 * 128);
                    unsigned int p3 = *(const unsigned int*)(fp + (size_t)s3 * 128);
                    acc0 += bf2f(p0 & 0xffffu); acc1 += bf2f(p0 >> 16);
                    acc0 += bf2f(p1 & 0xffffu); acc1 += bf2f(p1 >> 16);
                    acc0 += bf2f(p2 & 0xffffu); acc1 += bf2f(p2 >> 16);
                    acc0 += bf2f(p3 & 0xffffu); acc1 += bf2f(p3 >> 16);
                }
                for (; j < cnt; ++j) {
                    int s = __shfl(idx, j, 64);
                    unsigned int p = *(const unsigned int*)(fp + (size_t)s * 128);
                    acc0 += bf2f(p & 0xffffu); acc1 += bf2f(p >> 16);
                }
            }
            const int deg = end - beg;
            float inv = (deg > 0) ? 1.0f / (float)deg : 0.0f;  // ref: 0/max(0,1)=0
            unsigned int o = (unsigned)f2bf(acc0 * inv) |
                             ((unsigned)f2bf(acc1 * inv) << 16);
            *(unsigned int*)&smean[wave][mi][lane * 2] = o;
        }
    }
    __syncthreads();   // all waves reach this (inactive waves skip phase 1)

    // ---- phase 2: dual GEMM for this wave's 16 rows ----
    if (r0 >= N) return;
    const int mrow = lane & 15;
    const int quad = lane >> 4;
    const size_t rowS = (size_t)(r0 + mrow) * 128;

    floatx4 acc[8];
#pragma unroll
    for (int t = 0; t < 8; ++t) acc[t] = (floatx4)(0.0f);

#pragma unroll
    for (int kk = 0; kk < 4; ++kk) {
        const int k = kk * 32 + quad * 8;
        bf16x8 aA = *(const bf16x8*)&smean[wave][mrow][k];
        bf16x8 aS = *(const bf16x8*)(feat + rowS + k);
#pragma unroll
        for (int t = 0; t < 8; ++t) {
            bf16x8 bl = *(const bf16x8*)(Wl + (size_t)(t * 16 + mrow) * 128 + k);
            acc[t] = __builtin_amdgcn_mfma_f32_16x16x32_bf16(aA, bl, acc[t], 0, 0, 0);
            bf16x8 br = *(const bf16x8*)(Wr + (size_t)(t * 16 + mrow) * 128 + k);
            acc[t] = __builtin_amdgcn_mfma_f32_16x16x32_bf16(aS, br, acc[t], 0, 0, 0);
        }
    }

#pragma unroll
    for (int t = 0; t < 8; ++t) {
        float b = bias[t * 16 + mrow];
#pragma unroll
        for (int i = 0; i < 4; ++i) {
            float v = fmaxf(acc[t][i] + b, 0.0f);
            out[(size_t)(r0 + quad * 4 + i) * 128 + t * 16 + mrow] = f2bf(v);
        }
    }
}

// ---------------------------------------------------------------------------
// Head GEMM: out = inA @ W3^T + b3  (fp32 out, 64 cols)
__global__ __launch_bounds__(256) void head_gemm_kernel(
    const unsigned short* __restrict__ inA,
    const unsigned short* __restrict__ W,
    const float* __restrict__ bias,
    float* __restrict__ out,
    int M)
{
    const int wave = threadIdx.x >> 6;
    const int lane = threadIdx.x & 63;
    const int r0 = (blockIdx.x * 4 + wave) * 16;
    if (r0 >= M) return;
    const int mrow = lane & 15;
    const int quad = lane >> 4;
    const size_t rowA = (size_t)(r0 + mrow) * 128;

    floatx4 acc[4];
#pragma unroll
    for (int t = 0; t < 4; ++t) acc[t] = (floatx4)(0.0f);

#pragma unroll
    for (int kk = 0; kk < 4; ++kk) {
        const int k = kk * 32 + quad * 8;
        bf16x8 aA = *(const bf16x8*)(inA + rowA + k);
#pragma unroll
        for (int t = 0; t < 4; ++t) {
            bf16x8 b = *(const bf16x8*)(W + (size_t)(t * 16 + mrow) * 128 + k);
            acc[t] = __builtin_amdgcn_mfma_f32_16x16x32_bf16(aA, b, acc[t], 0, 0, 0);
        }
    }

#pragma unroll
    for (int t = 0; t < 4; ++t) {
        float b = bias[t * 16 + mrow];
#pragma unroll
        for (int i = 0; i < 4; ++i)
            out[(size_t)(r0 + quad * 4 + i) * 64 + t * 16 + mrow] = acc[t][i] + b;
    }
}

// ---------------------------------------------------------------------------
extern "C" void kernel_launch(void* const* d_in, const int* in_sizes, int n_in,
                              void* d_out, int out_size, void* d_ws, size_t ws_size,
                              hipStream_t stream)
{
    const float* x   = (const float*)d_in[0];
    const int* ei    = (const int*)d_in[1];
    const float* W1l = (const float*)d_in[2];
    const float* b1l = (const float*)d_in[3];
    const float* W1r = (const float*)d_in[4];
    const float* W2l = (const float*)d_in[5];
    const float* b2l = (const float*)d_in[6];
    const float* W2r = (const float*)d_in[7];
    const float* W3  = (const float*)d_in[8];
    const float* b3  = (const float*)d_in[9];
    float* out = (float*)d_out;

    const int N = in_sizes[0] / 128;   // 50000
    const int E = in_sizes[1] / 2;     // 640000
    const int* src = ei;
    const int* dst = ei + E;

    // workspace layout (all offsets 16B aligned):
    //   deg_i : N ints (pad x4)  partials: 64 ints
    //   rowptr: N+4 ints         cursor  : N ints
    //   csr   : E ints           xb/h1/h2: N*128 bf16 each
    //   wb    : 5 bf16 weight mats contiguous
    const int n4 = (N + 3) / 4;
    int* deg_i    = (int*)d_ws;
    int* partials = deg_i + n4 * 4;
    int* rowptr   = partials + 64;
    int* cursor   = rowptr + N + 4;
    int* csr      = cursor + n4 * 4;
    unsigned short* xb   = (unsigned short*)(csr + E);
    unsigned short* h1   = xb + (size_t)N * 128;
    unsigned short* h2   = h1 + (size_t)N * 128;
    unsigned short* wb1l = h2 + (size_t)N * 128;
    unsigned short* wb1r = wb1l + 16384;
    unsigned short* wb2l = wb1r + 16384;
    unsigned short* wb2r = wb2l + 16384;
    unsigned short* wb3  = wb2r + 16384;

    const int gblk = ((N + 15) / 16 + 3) / 4;   // 4 row-tiles per block
    const int eblk = (E + 255) / 256;
    const int NX4  = N * 32;                    // x in float4 units
    const int P    = (n4 + 255) / 256;          // scan blocks (<=64 for N<=65536)

    // ---- fused prologue: weight cvt + x cvt + deg zero (1 launch) ----
    {
        int total = WSEG + NX4 + n4;
        hipLaunchKernelGGL(prologue_kernel, dim3((total + 255) / 256), dim3(256), 0,
                           stream, W1l, W1r, W2l, W2r, W3, x, wb1l, xb, deg_i,
                           NX4, n4);
    }

    // ---- CSR build (once; reused by both layers) ----
    hipLaunchKernelGGL(hist_kernel, dim3(eblk), dim3(256), 0, stream, dst, deg_i, E);
    hipLaunchKernelGGL(scan_partial_kernel, dim3(P), dim3(256), 0, stream,
                       deg_i, partials, N);
    hipLaunchKernelGGL(scan_apply_kernel, dim3(P), dim3(256), 0, stream,
                       deg_i, partials, rowptr, cursor, N, P);
    hipLaunchKernelGGL(fill_kernel, dim3(eblk), dim3(256), 0, stream,
                       src, dst, cursor, csr, E);

    // ---- fused layers ----
    hipLaunchKernelGGL(sage_layer_kernel, dim3(gblk), dim3(256), 0, stream,
                       xb, rowptr, csr, wb1l, wb1r, b1l, h1, N);
    hipLaunchKernelGGL(sage_layer_kernel, dim3(gblk), dim3(256), 0, stream,
                       h1, rowptr, csr, wb2l, wb2r, b2l, h2, N);
    // ---- output head ----
    hipLaunchKernelGGL(head_gemm_kernel, dim3(gblk), dim3(256), 0, stream,
                       h2, wb3, b3, out, N);
}

// Round 7
// 286.809 us; speedup vs baseline: 1.1208x; 1.1208x over previous
//
#include <hip/hip_runtime.h>

// ---------------------------------------------------------------------------
// GNN_6305011991202: 2-layer GraphSAGE (mean aggr) + linear head. fp32 I/O.
//   h1 = relu(mean1 @ W1_l^T + b1_l + x  @ W1_r^T)
//   h2 = relu(mean2 @ W2_l^T + b2_l + h1 @ W2_r^T)
//   out = h2 @ W3^T + b3          (out: [50000, 64] fp32)
// R7: fused layer kernel rebalanced — 1 block per 16-row tile (3125 blocks),
// phase 1: 4 waves x 4 nodes gather (12500 gather waves, 4x R6), phase 2:
// waves split the 8 output col-tiles (2 each) from the shared LDS A-tile.
// ---------------------------------------------------------------------------

typedef __bf16 bf16x8 __attribute__((ext_vector_type(8)));
typedef float floatx4 __attribute__((ext_vector_type(4)));

__device__ __forceinline__ float bf2f(unsigned int u) {
    union { unsigned int i; float f; } c;
    c.i = u << 16;
    return c.f;
}
__device__ __forceinline__ unsigned short f2bf(float f) {
    union { float f; unsigned int i; } c;
    c.f = f;
    unsigned int i = c.i;
    unsigned int r = (i + 0x7fffu + ((i >> 16) & 1u)) >> 16;  // RNE
    return (unsigned short)r;
}
__device__ __forceinline__ ushort4 cvt4(float4 v) {
    ushort4 o;
    o.x = f2bf(v.x); o.y = f2bf(v.y); o.z = f2bf(v.z); o.w = f2bf(v.w);
    return o;
}

// ---------------------------------------------------------------------------
// Fused prologue: convert 5 weight mats (contiguous dst), convert x, zero deg.
#define WSEG 18432
__global__ __launch_bounds__(256) void prologue_kernel(
    const float* __restrict__ W1l, const float* __restrict__ W1r,
    const float* __restrict__ W2l, const float* __restrict__ W2r,
    const float* __restrict__ W3,  const float* __restrict__ x,
    unsigned short* __restrict__ wb,   // 5 weight dsts contiguous
    unsigned short* __restrict__ xb,
    int* __restrict__ deg, int NX4, int ND4)
{
    int i = blockIdx.x * 256 + threadIdx.x;
    if (i < WSEG) {
        const float* s; int l;
        if (i < 8192)       { if (i < 4096) { s = W1l; l = i; }
                              else          { s = W1r; l = i - 4096; } }
        else if (i < 16384) { if (i < 12288){ s = W2l; l = i - 8192; }
                              else          { s = W2r; l = i - 12288; } }
        else                { s = W3; l = i - 16384; }
        ((ushort4*)wb)[i] = cvt4(((const float4*)s)[l]);
        return;
    }
    int j = i - WSEG;
    if (j < NX4) { ((ushort4*)xb)[j] = cvt4(((const float4*)x)[j]); return; }
    int k = j - NX4;
    if (k < ND4) ((int4*)deg)[k] = make_int4(0, 0, 0, 0);
}

// ---------------------------------------------------------------------------
// CSR build step 1: degree histogram over dst
__global__ __launch_bounds__(256) void hist_kernel(const int* __restrict__ dst,
                                                   int* __restrict__ deg, int E) {
    int e = blockIdx.x * 256 + threadIdx.x;
    if (e < E) atomicAdd(deg + dst[e], 1);
}

// CSR scan A: per-block sums (1024 elems/block)
__global__ __launch_bounds__(256) void scan_partial_kernel(
    const int* __restrict__ deg, int* __restrict__ partials, int N)
{
    __shared__ int ws[4];
    const int t = threadIdx.x, lane = t & 63, wave = t >> 6;
    const int i4 = blockIdx.x * 256 + t;
    const int n4 = (N + 3) / 4;
    int s = 0;
    if (i4 < n4) {
        int b = i4 * 4;
        if (b + 3 < N) {
            int4 v = ((const int4*)deg)[i4];
            s = v.x + v.y + v.z + v.w;
        } else {
            for (int q = 0; q < 4 && b + q < N; ++q) s += deg[b + q];
        }
    }
#pragma unroll
    for (int off = 32; off > 0; off >>= 1) s += __shfl_xor(s, off, 64);
    if (lane == 0) ws[wave] = s;
    __syncthreads();
    if (t == 0) partials[blockIdx.x] = ws[0] + ws[1] + ws[2] + ws[3];
}

// CSR scan B+C merged: each block redundantly reduces partials[< blockIdx]
// (P <= 64), re-scans its 1024 elems, writes rowptr & cursor.
__global__ __launch_bounds__(256) void scan_apply_kernel(
    const int* __restrict__ deg, const int* __restrict__ partials,
    int* __restrict__ rowptr, int* __restrict__ cursor, int N, int P)
{
    __shared__ int woff[4];
    __shared__ int s_base;
    const int t = threadIdx.x, lane = t & 63, wave = t >> 6;
    const int i4 = blockIdx.x * 256 + t;
    const int n4 = (N + 3) / 4;
    const int b = i4 * 4;

    if (wave == 0) {          // exclusive sum of block partials below us
        int v = (lane < P && lane < (int)blockIdx.x) ? partials[lane] : 0;
#pragma unroll
        for (int off = 32; off > 0; off >>= 1) v += __shfl_xor(v, off, 64);
        if (lane == 0) s_base = v;
    }

    int4 v = make_int4(0, 0, 0, 0);
    if (i4 < n4) {
        if (b + 3 < N) v = ((const int4*)deg)[i4];
        else {
            if (b + 0 < N) v.x = deg[b + 0];
            if (b + 1 < N) v.y = deg[b + 1];
            if (b + 2 < N) v.z = deg[b + 2];
        }
    }
    const int p1 = v.x, p2 = v.x + v.y, p3 = v.x + v.y + v.z;
    const int tsum = p3 + v.w;
    int incl = tsum;
#pragma unroll
    for (int off = 1; off < 64; off <<= 1) {
        int tt = __shfl_up(incl, off, 64);
        if (lane >= off) incl += tt;
    }
    const int texcl = incl - tsum;
    if (lane == 63) woff[wave] = incl;
    __syncthreads();
    int wo = 0;
#pragma unroll
    for (int w = 0; w < 4; ++w) if (w < wave) wo += woff[w];
    const int e = s_base + wo + texcl;
    if (blockIdx.x == 0 && t == 0) rowptr[0] = 0;
    if (b + 3 < N) {
        ((int4*)cursor)[i4] = make_int4(e, e + p1, e + p2, e + p3);
        rowptr[b + 1] = e + p1;
        rowptr[b + 2] = e + p2;
        rowptr[b + 3] = e + p3;
        rowptr[b + 4] = e + tsum;
    } else if (b < N) {
        if (b + 0 < N) { cursor[b + 0] = e;      rowptr[b + 1] = e + p1; }
        if (b + 1 < N) { cursor[b + 1] = e + p1; rowptr[b + 2] = e + p2; }
        if (b + 2 < N) { cursor[b + 2] = e + p2; rowptr[b + 3] = e + p3; }
    }
}

// CSR build: scatter src ids into neighbor lists
__global__ __launch_bounds__(256) void fill_kernel(const int* __restrict__ src,
                                                   const int* __restrict__ dst,
                                                   int* __restrict__ cursor,
                                                   int* __restrict__ csr, int E) {
    int e = blockIdx.x * 256 + threadIdx.x;
    if (e >= E) return;
    int pos = atomicAdd(cursor + dst[e], 1);
    csr[pos] = src[e];
}

// ---------------------------------------------------------------------------
// Fused SAGE layer: out = relu( mean(feat,nbrs) @ Wl^T + bias + feat @ Wr^T )
// One block per 16-row tile (grid = ceil(N/16)).
// Phase 1: wave w gathers nodes r0+4w..r0+4w+3 (lane = 2 feature cols, one
//   coalesced 256B row read per neighbor, 4-deep ILP) -> bf16 into LDS tile.
// Phase 2: wave w computes output col-tiles {2w, 2w+1} (dual Wl/Wr MFMA),
//   A-fragments from the shared LDS tile, self-fragments from global.
// LDS row stride 136 shorts (+8 pad). mfma_f32_16x16x32_bf16 layout
// (HW-verified m89/m91): A/B elem [m=lane&15][k=(lane>>4)*8+j];
// C/D [row=(lane>>4)*4+reg][col=lane&15].
__global__ __launch_bounds__(256) void sage_layer_kernel(
    const unsigned short* __restrict__ feat,   // [N,128] bf16 (gather + self)
    const int* __restrict__ rowptr, const int* __restrict__ csr,
    const unsigned short* __restrict__ Wl,
    const unsigned short* __restrict__ Wr,
    const float* __restrict__ bias,
    unsigned short* __restrict__ out,          // [N,128] bf16
    int N)
{
    __shared__ unsigned short smean[16][136];
    const int wave = threadIdx.x >> 6;
    const int lane = threadIdx.x & 63;
    const int r0 = blockIdx.x * 16;

    // ---- phase 1: this wave gathers 4 of the block's 16 nodes ----
    {
        const unsigned short* fp = feat + lane * 2;
#pragma unroll
        for (int q = 0; q < 4; ++q) {
            const int mi = wave * 4 + q;
            const int n = r0 + mi;
            if (n >= N) break;
            const int beg = rowptr[n], end = rowptr[n + 1];
            float acc0 = 0.f, acc1 = 0.f;
            for (int j0 = beg; j0 < end; j0 += 64) {
                int cnt = min(64, end - j0);
                int idx = (lane < cnt) ? csr[j0 + lane] : 0;
                int j = 0;
                for (; j + 4 <= cnt; j += 4) {
                    int s0 = __shfl(idx, j + 0, 64);
                    int s1 = __shfl(idx, j + 1, 64);
                    int s2 = __shfl(idx, j + 2, 64);
                    int s3 = __shfl(idx, j + 3, 64);
                    unsigned int p0 = *(const unsigned int*)(fp + (size_t)s0 * 128);
                    unsigned int p1 = *(const unsigned int*)(fp + (size_t)s1 * 128);
                    unsigned int p2 = *(const unsigned int*)(fp + (size_t)s2 * 128);
                    unsigned int p3 = *(const unsigned int*)(fp + (size_t)s3 * 128);
                    acc0 += bf2f(p0 & 0xffffu); acc1 += bf2f(p0 >> 16);
                    acc0 += bf2f(p1 & 0xffffu); acc1 += bf2f(p1 >> 16);
                    acc0 += bf2f(p2 & 0xffffu); acc1 += bf2f(p2 >> 16);
                    acc0 += bf2f(p3 & 0xffffu); acc1 += bf2f(p3 >> 16);
                }
                for (; j < cnt; ++j) {
                    int s = __shfl(idx, j, 64);
                    unsigned int p = *(const unsigned int*)(fp + (size_t)s * 128);
                    acc0 += bf2f(p & 0xffffu); acc1 += bf2f(p >> 16);
                }
            }
            const int deg = end - beg;
            float inv = (deg > 0) ? 1.0f / (float)deg : 0.0f;  // ref: 0/max(0,1)=0
            unsigned int o = (unsigned)f2bf(acc0 * inv) |
                             ((unsigned)f2bf(acc1 * inv) << 16);
            *(unsigned int*)&smean[mi][lane * 2] = o;
        }
    }
    __syncthreads();

    // ---- phase 2: this wave computes col-tiles 2*wave, 2*wave+1 ----
    const int mrow = lane & 15;
    const int quad = lane >> 4;
    int selfRow = r0 + mrow;
    if (selfRow >= N) selfRow = N - 1;      // partial-tile clamp (loads only)
    const size_t rowS = (size_t)selfRow * 128;

    floatx4 acc0 = (floatx4)(0.0f), acc1 = (floatx4)(0.0f);
    const int t0 = wave * 2, t1 = wave * 2 + 1;

#pragma unroll
    for (int kk = 0; kk < 4; ++kk) {
        const int k = kk * 32 + quad * 8;
        bf16x8 aA = *(const bf16x8*)&smean[mrow][k];
        bf16x8 aS = *(const bf16x8*)(feat + rowS + k);
        bf16x8 bl0 = *(const bf16x8*)(Wl + (size_t)(t0 * 16 + mrow) * 128 + k);
        acc0 = __builtin_amdgcn_mfma_f32_16x16x32_bf16(aA, bl0, acc0, 0, 0, 0);
        bf16x8 br0 = *(const bf16x8*)(Wr + (size_t)(t0 * 16 + mrow) * 128 + k);
        acc0 = __builtin_amdgcn_mfma_f32_16x16x32_bf16(aS, br0, acc0, 0, 0, 0);
        bf16x8 bl1 = *(const bf16x8*)(Wl + (size_t)(t1 * 16 + mrow) * 128 + k);
        acc1 = __builtin_amdgcn_mfma_f32_16x16x32_bf16(aA, bl1, acc1, 0, 0, 0);
        bf16x8 br1 = *(const bf16x8*)(Wr + (size_t)(t1 * 16 + mrow) * 128 + k);
        acc1 = __builtin_amdgcn_mfma_f32_16x16x32_bf16(aS, br1, acc1, 0, 0, 0);
    }

    const float b0 = bias[t0 * 16 + mrow];
    const float b1 = bias[t1 * 16 + mrow];
#pragma unroll
    for (int i = 0; i < 4; ++i) {
        const int r = r0 + quad * 4 + i;
        if (r < N) {
            out[(size_t)r * 128 + t0 * 16 + mrow] = f2bf(fmaxf(acc0[i] + b0, 0.0f));
            out[(size_t)r * 128 + t1 * 16 + mrow] = f2bf(fmaxf(acc1[i] + b1, 0.0f));
        }
    }
}

// ---------------------------------------------------------------------------
// Head GEMM: out = inA @ W3^T + b3  (fp32 out, 64 cols)
__global__ __launch_bounds__(256) void head_gemm_kernel(
    const unsigned short* __restrict__ inA,
    const unsigned short* __restrict__ W,
    const float* __restrict__ bias,
    float* __restrict__ out,
    int M)
{
    const int wave = threadIdx.x >> 6;
    const int lane = threadIdx.x & 63;
    const int r0 = (blockIdx.x * 4 + wave) * 16;
    if (r0 >= M) return;
    const int mrow = lane & 15;
    const int quad = lane >> 4;
    const size_t rowA = (size_t)(r0 + mrow) * 128;

    floatx4 acc[4];
#pragma unroll
    for (int t = 0; t < 4; ++t) acc[t] = (floatx4)(0.0f);

#pragma unroll
    for (int kk = 0; kk < 4; ++kk) {
        const int k = kk * 32 + quad * 8;
        bf16x8 aA = *(const bf16x8*)(inA + rowA + k);
#pragma unroll
        for (int t = 0; t < 4; ++t) {
            bf16x8 b = *(const bf16x8*)(W + (size_t)(t * 16 + mrow) * 128 + k);
            acc[t] = __builtin_amdgcn_mfma_f32_16x16x32_bf16(aA, b, acc[t], 0, 0, 0);
        }
    }

#pragma unroll
    for (int t = 0; t < 4; ++t) {
        float b = bias[t * 16 + mrow];
#pragma unroll
        for (int i = 0; i < 4; ++i)
            out[(size_t)(r0 + quad * 4 + i) * 64 + t * 16 + mrow] = acc[t][i] + b;
    }
}

// ---------------------------------------------------------------------------
extern "C" void kernel_launch(void* const* d_in, const int* in_sizes, int n_in,
                              void* d_out, int out_size, void* d_ws, size_t ws_size,
                              hipStream_t stream)
{
    const float* x   = (const float*)d_in[0];
    const int* ei    = (const int*)d_in[1];
    const float* W1l = (const float*)d_in[2];
    const float* b1l = (const float*)d_in[3];
    const float* W1r = (const float*)d_in[4];
    const float* W2l = (const float*)d_in[5];
    const float* b2l = (const float*)d_in[6];
    const float* W2r = (const float*)d_in[7];
    const float* W3  = (const float*)d_in[8];
    const float* b3  = (const float*)d_in[9];
    float* out = (float*)d_out;

    const int N = in_sizes[0] / 128;   // 50000
    const int E = in_sizes[1] / 2;     // 640000
    const int* src = ei;
    const int* dst = ei + E;

    // workspace layout (all offsets 16B aligned):
    //   deg_i : N ints (pad x4)  partials: 64 ints
    //   rowptr: N+4 ints         cursor  : N ints
    //   csr   : E ints           xb/h1/h2: N*128 bf16 each
    //   wb    : 5 bf16 weight mats contiguous
    const int n4 = (N + 3) / 4;
    int* deg_i    = (int*)d_ws;
    int* partials = deg_i + n4 * 4;
    int* rowptr   = partials + 64;
    int* cursor   = rowptr + N + 4;
    int* csr      = cursor + n4 * 4;
    unsigned short* xb   = (unsigned short*)(csr + E);
    unsigned short* h1   = xb + (size_t)N * 128;
    unsigned short* h2   = h1 + (size_t)N * 128;
    unsigned short* wb1l = h2 + (size_t)N * 128;
    unsigned short* wb1r = wb1l + 16384;
    unsigned short* wb2l = wb1r + 16384;
    unsigned short* wb2r = wb2l + 16384;
    unsigned short* wb3  = wb2r + 16384;

    const int lblk = (N + 15) / 16;             // fused layer: 1 tile/block
    const int gblk = ((N + 15) / 16 + 3) / 4;   // head: 4 tiles/block
    const int eblk = (E + 255) / 256;
    const int NX4  = N * 32;                    // x in float4 units
    const int P    = (n4 + 255) / 256;          // scan blocks (<=64 for N<=65536)

    // ---- fused prologue: weight cvt + x cvt + deg zero (1 launch) ----
    {
        int total = WSEG + NX4 + n4;
        hipLaunchKernelGGL(prologue_kernel, dim3((total + 255) / 256), dim3(256), 0,
                           stream, W1l, W1r, W2l, W2r, W3, x, wb1l, xb, deg_i,
                           NX4, n4);
    }

    // ---- CSR build (once; reused by both layers) ----
    hipLaunchKernelGGL(hist_kernel, dim3(eblk), dim3(256), 0, stream, dst, deg_i, E);
    hipLaunchKernelGGL(scan_partial_kernel, dim3(P), dim3(256), 0, stream,
                       deg_i, partials, N);
    hipLaunchKernelGGL(scan_apply_kernel, dim3(P), dim3(256), 0, stream,
                       deg_i, partials, rowptr, cursor, N, P);
    hipLaunchKernelGGL(fill_kernel, dim3(eblk), dim3(256), 0, stream,
                       src, dst, cursor, csr, E);

    // ---- fused layers ----
    hipLaunchKernelGGL(sage_layer_kernel, dim3(lblk), dim3(256), 0, stream,
                       xb, rowptr, csr, wb1l, wb1r, b1l, h1, N);
    hipLaunchKernelGGL(sage_layer_kernel, dim3(lblk), dim3(256), 0, stream,
                       h1, rowptr, csr, wb2l, wb2r, b2l, h2, N);
    // ---- output head ----
    hipLaunchKernelGGL(head_gemm_kernel, dim3(gblk), dim3(256), 0, stream,
                       h2, wb3, b3, out, N);
}

// Round 8
// 282.649 us; speedup vs baseline: 1.1373x; 1.0147x over previous
//
#include <hip/hip_runtime.h>

// ---------------------------------------------------------------------------
// GNN_6305011991202: 2-layer GraphSAGE (mean aggr) + linear head. fp32 I/O.
//   h1 = relu(mean1 @ W1_l^T + b1_l + x  @ W1_r^T)
//   h2 = relu(mean2 @ W2_l^T + b2_l + h1 @ W2_r^T)
//   out = h2 @ W3^T + b3          (out: [50000, 64] fp32)
// R8: gather inner loop restructured — lane = (nbr_slot, col_group): one
// dwordx4 wave-load fetches 4 neighbor rows (16B x 16 lanes each), indices
// read directly from csr (no ds_bpermute), 16 neighbors in flight. Cross-slot
// shfl_xor reduce at node end.
// ---------------------------------------------------------------------------

typedef __bf16 bf16x8 __attribute__((ext_vector_type(8)));
typedef float floatx4 __attribute__((ext_vector_type(4)));

__device__ __forceinline__ float bf2f(unsigned int u) {
    union { unsigned int i; float f; } c;
    c.i = u << 16;
    return c.f;
}
__device__ __forceinline__ unsigned short f2bf(float f) {
    union { float f; unsigned int i; } c;
    c.f = f;
    unsigned int i = c.i;
    unsigned int r = (i + 0x7fffu + ((i >> 16) & 1u)) >> 16;  // RNE
    return (unsigned short)r;
}
__device__ __forceinline__ ushort4 cvt4(float4 v) {
    ushort4 o;
    o.x = f2bf(v.x); o.y = f2bf(v.y); o.z = f2bf(v.z); o.w = f2bf(v.w);
    return o;
}

// ---------------------------------------------------------------------------
// Fused prologue: convert 5 weight mats (contiguous dst), convert x, zero deg.
#define WSEG 18432
__global__ __launch_bounds__(256) void prologue_kernel(
    const float* __restrict__ W1l, const float* __restrict__ W1r,
    const float* __restrict__ W2l, const float* __restrict__ W2r,
    const float* __restrict__ W3,  const float* __restrict__ x,
    unsigned short* __restrict__ wb,   // 5 weight dsts contiguous
    unsigned short* __restrict__ xb,
    int* __restrict__ deg, int NX4, int ND4)
{
    int i = blockIdx.x * 256 + threadIdx.x;
    if (i < WSEG) {
        const float* s; int l;
        if (i < 8192)       { if (i < 4096) { s = W1l; l = i; }
                              else          { s = W1r; l = i - 4096; } }
        else if (i < 16384) { if (i < 12288){ s = W2l; l = i - 8192; }
                              else          { s = W2r; l = i - 12288; } }
        else                { s = W3; l = i - 16384; }
        ((ushort4*)wb)[i] = cvt4(((const float4*)s)[l]);
        return;
    }
    int j = i - WSEG;
    if (j < NX4) { ((ushort4*)xb)[j] = cvt4(((const float4*)x)[j]); return; }
    int k = j - NX4;
    if (k < ND4) ((int4*)deg)[k] = make_int4(0, 0, 0, 0);
}

// ---------------------------------------------------------------------------
// CSR build step 1: degree histogram over dst
__global__ __launch_bounds__(256) void hist_kernel(const int* __restrict__ dst,
                                                   int* __restrict__ deg, int E) {
    int e = blockIdx.x * 256 + threadIdx.x;
    if (e < E) atomicAdd(deg + dst[e], 1);
}

// CSR scan A: per-block sums (1024 elems/block)
__global__ __launch_bounds__(256) void scan_partial_kernel(
    const int* __restrict__ deg, int* __restrict__ partials, int N)
{
    __shared__ int ws[4];
    const int t = threadIdx.x, lane = t & 63, wave = t >> 6;
    const int i4 = blockIdx.x * 256 + t;
    const int n4 = (N + 3) / 4;
    int s = 0;
    if (i4 < n4) {
        int b = i4 * 4;
        if (b + 3 < N) {
            int4 v = ((const int4*)deg)[i4];
            s = v.x + v.y + v.z + v.w;
        } else {
            for (int q = 0; q < 4 && b + q < N; ++q) s += deg[b + q];
        }
    }
#pragma unroll
    for (int off = 32; off > 0; off >>= 1) s += __shfl_xor(s, off, 64);
    if (lane == 0) ws[wave] = s;
    __syncthreads();
    if (t == 0) partials[blockIdx.x] = ws[0] + ws[1] + ws[2] + ws[3];
}

// CSR scan B+C merged: each block redundantly reduces partials[< blockIdx]
// (P <= 64), re-scans its 1024 elems, writes rowptr & cursor.
__global__ __launch_bounds__(256) void scan_apply_kernel(
    const int* __restrict__ deg, const int* __restrict__ partials,
    int* __restrict__ rowptr, int* __restrict__ cursor, int N, int P)
{
    __shared__ int woff[4];
    __shared__ int s_base;
    const int t = threadIdx.x, lane = t & 63, wave = t >> 6;
    const int i4 = blockIdx.x * 256 + t;
    const int n4 = (N + 3) / 4;
    const int b = i4 * 4;

    if (wave == 0) {          // exclusive sum of block partials below us
        int v = (lane < P && lane < (int)blockIdx.x) ? partials[lane] : 0;
#pragma unroll
        for (int off = 32; off > 0; off >>= 1) v += __shfl_xor(v, off, 64);
        if (lane == 0) s_base = v;
    }

    int4 v = make_int4(0, 0, 0, 0);
    if (i4 < n4) {
        if (b + 3 < N) v = ((const int4*)deg)[i4];
        else {
            if (b + 0 < N) v.x = deg[b + 0];
            if (b + 1 < N) v.y = deg[b + 1];
            if (b + 2 < N) v.z = deg[b + 2];
        }
    }
    const int p1 = v.x, p2 = v.x + v.y, p3 = v.x + v.y + v.z;
    const int tsum = p3 + v.w;
    int incl = tsum;
#pragma unroll
    for (int off = 1; off < 64; off <<= 1) {
        int tt = __shfl_up(incl, off, 64);
        if (lane >= off) incl += tt;
    }
    const int texcl = incl - tsum;
    if (lane == 63) woff[wave] = incl;
    __syncthreads();
    int wo = 0;
#pragma unroll
    for (int w = 0; w < 4; ++w) if (w < wave) wo += woff[w];
    const int e = s_base + wo + texcl;
    if (blockIdx.x == 0 && t == 0) rowptr[0] = 0;
    if (b + 3 < N) {
        ((int4*)cursor)[i4] = make_int4(e, e + p1, e + p2, e + p3);
        rowptr[b + 1] = e + p1;
        rowptr[b + 2] = e + p2;
        rowptr[b + 3] = e + p3;
        rowptr[b + 4] = e + tsum;
    } else if (b < N) {
        if (b + 0 < N) { cursor[b + 0] = e;      rowptr[b + 1] = e + p1; }
        if (b + 1 < N) { cursor[b + 1] = e + p1; rowptr[b + 2] = e + p2; }
        if (b + 2 < N) { cursor[b + 2] = e + p2; rowptr[b + 3] = e + p3; }
    }
}

// CSR build: scatter src ids into neighbor lists
__global__ __launch_bounds__(256) void fill_kernel(const int* __restrict__ src,
                                                   const int* __restrict__ dst,
                                                   int* __restrict__ cursor,
                                                   int* __restrict__ csr, int E) {
    int e = blockIdx.x * 256 + threadIdx.x;
    if (e >= E) return;
    int pos = atomicAdd(cursor + dst[e], 1);
    csr[pos] = src[e];
}

// ---------------------------------------------------------------------------
// Fused SAGE layer: out = relu( mean(feat,nbrs) @ Wl^T + bias + feat @ Wr^T )
// One block per 16-row tile (grid = ceil(N/16)).
// Phase 1 (gather, wave w -> nodes r0+4w..r0+4w+3): 2-D lane split
//   grp = lane>>4 (neighbor slot 0..3), col = lane&15 (8 feature cols, 16B).
//   One dwordx4 wave-load fetches 4 neighbor rows; indices straight from csr
//   (contiguous -> L1 broadcast, NO ds_bpermute). 4 chunks unrolled = 16
//   neighbors in flight. OOB slots clamp to beg + zero-mask (bf16 0 == 0x0).
//   Node end: shfl_xor(16/32) cross-slot reduce, lanes<16 write mean to LDS.
// Phase 2: wave w computes output col-tiles {2w, 2w+1} (dual Wl/Wr MFMA),
//   A-fragments from the shared LDS tile, self-fragments from global.
// mfma_f32_16x16x32_bf16 layout (HW-verified m89/m91):
//   A/B elem [m=lane&15][k=(lane>>4)*8+j]; C/D [row=(lane>>4)*4+reg][col=lane&15].
__global__ __launch_bounds__(256) void sage_layer_kernel(
    const unsigned short* __restrict__ feat,   // [N,128] bf16 (gather + self)
    const int* __restrict__ rowptr, const int* __restrict__ csr,
    const unsigned short* __restrict__ Wl,
    const unsigned short* __restrict__ Wr,
    const float* __restrict__ bias,
    unsigned short* __restrict__ out,          // [N,128] bf16
    int N)
{
    __shared__ unsigned short smean[16][136];
    const int wave = threadIdx.x >> 6;
    const int lane = threadIdx.x & 63;
    const int r0 = blockIdx.x * 16;

    // ---- phase 1: this wave gathers 4 of the block's 16 nodes ----
    {
        const int grp = lane >> 4;          // neighbor slot
        const int col = lane & 15;          // 8-col group (16B)
        const unsigned short* fq = feat + col * 8;
#pragma unroll
        for (int q = 0; q < 4; ++q) {
            const int mi = wave * 4 + q;
            const int n = r0 + mi;
            if (n >= N) break;
            const int beg = rowptr[n], end = rowptr[n + 1];
            const int deg = end - beg;
            float a0 = 0.f, a1 = 0.f, a2 = 0.f, a3 = 0.f;
            float a4 = 0.f, a5 = 0.f, a6 = 0.f, a7 = 0.f;
            // chunks of 4 neighbors; 4 chunks (16 nbrs) in flight
            for (int jA = beg + grp; jA < end; jA += 16) {
                const int jB = jA + 4, jC = jA + 8, jD = jA + 12;
                const unsigned mB = (jB < end) ? 0xffffffffu : 0u;
                const unsigned mC = (jC < end) ? 0xffffffffu : 0u;
                const unsigned mD = (jD < end) ? 0xffffffffu : 0u;
                const int iA = csr[jA];
                const int iB = csr[mB ? jB : beg];
                const int iC = csr[mC ? jC : beg];
                const int iD = csr[mD ? jD : beg];
                uint4 pA = *(const uint4*)(fq + (size_t)iA * 128);
                uint4 pB = *(const uint4*)(fq + (size_t)iB * 128);
                uint4 pC = *(const uint4*)(fq + (size_t)iC * 128);
                uint4 pD = *(const uint4*)(fq + (size_t)iD * 128);
                pB.x &= mB; pB.y &= mB; pB.z &= mB; pB.w &= mB;
                pC.x &= mC; pC.y &= mC; pC.z &= mC; pC.w &= mC;
                pD.x &= mD; pD.y &= mD; pD.z &= mD; pD.w &= mD;
                a0 += bf2f(pA.x & 0xffff0000u ? pA.x << 16 : pA.x << 16);
                // (expanded below without the dummy select)
                a0 += 0.0f;
                // -- unpack & accumulate (lo = d<<16 bits, hi = d&0xffff0000) --
                {
                    a0 += bf2f(pA.x & 0xffffu); a1 += bf2f(pA.x >> 16);
                    a2 += bf2f(pA.y & 0xffffu); a3 += bf2f(pA.y >> 16);
                    a4 += bf2f(pA.z & 0xffffu); a5 += bf2f(pA.z >> 16);
                    a6 += bf2f(pA.w & 0xffffu); a7 += bf2f(pA.w >> 16);
                    a0 += bf2f(pB.x & 0xffffu); a1 += bf2f(pB.x >> 16);
                    a2 += bf2f(pB.y & 0xffffu); a3 += bf2f(pB.y >> 16);
                    a4 += bf2f(pB.z & 0xffffu); a5 += bf2f(pB.z >> 16);
                    a6 += bf2f(pB.w & 0xffffu); a7 += bf2f(pB.w >> 16);
                    a0 += bf2f(pC.x & 0xffffu); a1 += bf2f(pC.x >> 16);
                    a2 += bf2f(pC.y & 0xffffu); a3 += bf2f(pC.y >> 16);
                    a4 += bf2f(pC.z & 0xffffu); a5 += bf2f(pC.z >> 16);
                    a6 += bf2f(pC.w & 0xffffu); a7 += bf2f(pC.w >> 16);
                    a0 += bf2f(pD.x & 0xffffu); a1 += bf2f(pD.x >> 16);
                    a2 += bf2f(pD.y & 0xffffu); a3 += bf2f(pD.y >> 16);
                    a4 += bf2f(pD.z & 0xffffu); a5 += bf2f(pD.z >> 16);
                    a6 += bf2f(pD.w & 0xffffu); a7 += bf2f(pD.w >> 16);
                }
            }
            // cross-slot reduce (lanes differing in bits 4,5 hold other slots)
            a0 += __shfl_xor(a0, 16, 64); a0 += __shfl_xor(a0, 32, 64);
            a1 += __shfl_xor(a1, 16, 64); a1 += __shfl_xor(a1, 32, 64);
            a2 += __shfl_xor(a2, 16, 64); a2 += __shfl_xor(a2, 32, 64);
            a3 += __shfl_xor(a3, 16, 64); a3 += __shfl_xor(a3, 32, 64);
            a4 += __shfl_xor(a4, 16, 64); a4 += __shfl_xor(a4, 32, 64);
            a5 += __shfl_xor(a5, 16, 64); a5 += __shfl_xor(a5, 32, 64);
            a6 += __shfl_xor(a6, 16, 64); a6 += __shfl_xor(a6, 32, 64);
            a7 += __shfl_xor(a7, 16, 64); a7 += __shfl_xor(a7, 32, 64);
            if (grp == 0) {
                const float inv = (deg > 0) ? 1.0f / (float)deg : 0.0f;
                uint4 o;
                o.x = (unsigned)f2bf(a0 * inv) | ((unsigned)f2bf(a1 * inv) << 16);
                o.y = (unsigned)f2bf(a2 * inv) | ((unsigned)f2bf(a3 * inv) << 16);
                o.z = (unsigned)f2bf(a4 * inv) | ((unsigned)f2bf(a5 * inv) << 16);
                o.w = (unsigned)f2bf(a6 * inv) | ((unsigned)f2bf(a7 * inv) << 16);
                *(uint4*)&smean[mi][col * 8] = o;
            }
        }
    }
    __syncthreads();

    // ---- phase 2: this wave computes col-tiles 2*wave, 2*wave+1 ----
    const int mrow = lane & 15;
    const int quad = lane >> 4;
    int selfRow = r0 + mrow;
    if (selfRow >= N) selfRow = N - 1;      // partial-tile clamp (loads only)
    const size_t rowS = (size_t)selfRow * 128;

    floatx4 acc0 = (floatx4)(0.0f), acc1 = (floatx4)(0.0f);
    const int t0 = wave * 2, t1 = wave * 2 + 1;

#pragma unroll
    for (int kk = 0; kk < 4; ++kk) {
        const int k = kk * 32 + quad * 8;
        bf16x8 aA = *(const bf16x8*)&smean[mrow][k];
        bf16x8 aS = *(const bf16x8*)(feat + rowS + k);
        bf16x8 bl0 = *(const bf16x8*)(Wl + (size_t)(t0 * 16 + mrow) * 128 + k);
        acc0 = __builtin_amdgcn_mfma_f32_16x16x32_bf16(aA, bl0, acc0, 0, 0, 0);
        bf16x8 br0 = *(const bf16x8*)(Wr + (size_t)(t0 * 16 + mrow) * 128 + k);
        acc0 = __builtin_amdgcn_mfma_f32_16x16x32_bf16(aS, br0, acc0, 0, 0, 0);
        bf16x8 bl1 = *(const bf16x8*)(Wl + (size_t)(t1 * 16 + mrow) * 128 + k);
        acc1 = __builtin_amdgcn_mfma_f32_16x16x32_bf16(aA, bl1, acc1, 0, 0, 0);
        bf16x8 br1 = *(const bf16x8*)(Wr + (size_t)(t1 * 16 + mrow) * 128 + k);
        acc1 = __builtin_amdgcn_mfma_f32_16x16x32_bf16(aS, br1, acc1, 0, 0, 0);
    }

    const float b0 = bias[t0 * 16 + mrow];
    const float b1 = bias[t1 * 16 + mrow];
#pragma unroll
    for (int i = 0; i < 4; ++i) {
        const int r = r0 + quad * 4 + i;
        if (r < N) {
            out[(size_t)r * 128 + t0 * 16 + mrow] = f2bf(fmaxf(acc0[i] + b0, 0.0f));
            out[(size_t)r * 128 + t1 * 16 + mrow] = f2bf(fmaxf(acc1[i] + b1, 0.0f));
        }
    }
}

// ---------------------------------------------------------------------------
// Head GEMM: out = inA @ W3^T + b3  (fp32 out, 64 cols)
__global__ __launch_bounds__(256) void head_gemm_kernel(
    const unsigned short* __restrict__ inA,
    const unsigned short* __restrict__ W,
    const float* __restrict__ bias,
    float* __restrict__ out,
    int M)
{
    const int wave = threadIdx.x >> 6;
    const int lane = threadIdx.x & 63;
    const int r0 = (blockIdx.x * 4 + wave) * 16;
    if (r0 >= M) return;
    const int mrow = lane & 15;
    const int quad = lane >> 4;
    const size_t rowA = (size_t)(r0 + mrow) * 128;

    floatx4 acc[4];
#pragma unroll
    for (int t = 0; t < 4; ++t) acc[t] = (floatx4)(0.0f);

#pragma unroll
    for (int kk = 0; kk < 4; ++kk) {
        const int k = kk * 32 + quad * 8;
        bf16x8 aA = *(const bf16x8*)(inA + rowA + k);
#pragma unroll
        for (int t = 0; t < 4; ++t) {
            bf16x8 b = *(const bf16x8*)(W + (size_t)(t * 16 + mrow) * 128 + k);
            acc[t] = __builtin_amdgcn_mfma_f32_16x16x32_bf16(aA, b, acc[t], 0, 0, 0);
        }
    }

#pragma unroll
    for (int t = 0; t < 4; ++t) {
        float b = bias[t * 16 + mrow];
#pragma unroll
        for (int i = 0; i < 4; ++i)
            out[(size_t)(r0 + quad * 4 + i) * 64 + t * 16 + mrow] = acc[t][i] + b;
    }
}

// ---------------------------------------------------------------------------
extern "C" void kernel_launch(void* const* d_in, const int* in_sizes, int n_in,
                              void* d_out, int out_size, void* d_ws, size_t ws_size,
                              hipStream_t stream)
{
    const float* x   = (const float*)d_in[0];
    const int* ei    = (const int*)d_in[1];
    const float* W1l = (const float*)d_in[2];
    const float* b1l = (const float*)d_in[3];
    const float* W1r = (const float*)d_in[4];
    const float* W2l = (const float*)d_in[5];
    const float* b2l = (const float*)d_in[6];
    const float* W2r = (const float*)d_in[7];
    const float* W3  = (const float*)d_in[8];
    const float* b3  = (const float*)d_in[9];
    float* out = (float*)d_out;

    const int N = in_sizes[0] / 128;   // 50000
    const int E = in_sizes[1] / 2;     // 640000
    const int* src = ei;
    const int* dst = ei + E;

    // workspace layout (all offsets 16B aligned):
    //   deg_i : N ints (pad x4)  partials: 64 ints
    //   rowptr: N+4 ints         cursor  : N ints
    //   csr   : E ints           xb/h1/h2: N*128 bf16 each
    //   wb    : 5 bf16 weight mats contiguous
    const int n4 = (N + 3) / 4;
    int* deg_i    = (int*)d_ws;
    int* partials = deg_i + n4 * 4;
    int* rowptr   = partials + 64;
    int* cursor   = rowptr + N + 4;
    int* csr      = cursor + n4 * 4;
    unsigned short* xb   = (unsigned short*)(csr + E);
    unsigned short* h1   = xb + (size_t)N * 128;
    unsigned short* h2   = h1 + (size_t)N * 128;
    unsigned short* wb1l = h2 + (size_t)N * 128;
    unsigned short* wb1r = wb1l + 16384;
    unsigned short* wb2l = wb1r + 16384;
    unsigned short* wb2r = wb2l + 16384;
    unsigned short* wb3  = wb2r + 16384;

    const int lblk = (N + 15) / 16;             // fused layer: 1 tile/block
    const int gblk = ((N + 15) / 16 + 3) / 4;   // head: 4 tiles/block
    const int eblk = (E + 255) / 256;
    const int NX4  = N * 32;                    // x in float4 units
    const int P    = (n4 + 255) / 256;          // scan blocks (<=64 for N<=65536)

    // ---- fused prologue: weight cvt + x cvt + deg zero (1 launch) ----
    {
        int total = WSEG + NX4 + n4;
        hipLaunchKernelGGL(prologue_kernel, dim3((total + 255) / 256), dim3(256), 0,
                           stream, W1l, W1r, W2l, W2r, W3, x, wb1l, xb, deg_i,
                           NX4, n4);
    }

    // ---- CSR build (once; reused by both layers) ----
    hipLaunchKernelGGL(hist_kernel, dim3(eblk), dim3(256), 0, stream, dst, deg_i, E);
    hipLaunchKernelGGL(scan_partial_kernel, dim3(P), dim3(256), 0, stream,
                       deg_i, partials, N);
    hipLaunchKernelGGL(scan_apply_kernel, dim3(P), dim3(256), 0, stream,
                       deg_i, partials, rowptr, cursor, N, P);
    hipLaunchKernelGGL(fill_kernel, dim3(eblk), dim3(256), 0, stream,
                       src, dst, cursor, csr, E);

    // ---- fused layers ----
    hipLaunchKernelGGL(sage_layer_kernel, dim3(lblk), dim3(256), 0, stream,
                       xb, rowptr, csr, wb1l, wb1r, b1l, h1, N);
    hipLaunchKernelGGL(sage_layer_kernel, dim3(lblk), dim3(256), 0, stream,
                       h1, rowptr, csr, wb2l, wb2r, b2l, h2, N);
    // ---- output head ----
    hipLaunchKernelGGL(head_gemm_kernel, dim3(gblk), dim3(256), 0, stream,
                       h2, wb3, b3, out, N);
}

// Round 9
// 281.763 us; speedup vs baseline: 1.1408x; 1.0031x over previous
//
#include <hip/hip_runtime.h>
#include <hip/hip_fp16.h>

// ---------------------------------------------------------------------------
// GNN_6305011991202: 2-layer GraphSAGE (mean aggr) + linear head. fp32 I/O.
//   h1 = relu(mean1 @ W1_l^T + b1_l + x  @ W1_r^T)
//   h2 = relu(mean2 @ W2_l^T + b2_l + h1 @ W2_r^T)
//   out = h2 @ W3^T + b3          (out: [50000, 64] fp32)
// R9: f16 everywhere (better mantissa than bf16, same bytes). Gather
// accumulates in PACKED f16 (__hadd2 -> v_pk_add_f16): 1 VALU per 2 cols vs
// 4 for bf16 unpack — ~3x fewer hot-loop instructions. MFMA: 16x16x32_f16.
// ---------------------------------------------------------------------------

typedef _Float16 f16x8 __attribute__((ext_vector_type(8)));
typedef float floatx4 __attribute__((ext_vector_type(4)));

__device__ __forceinline__ unsigned short f2h(float f) {
    __half h = __float2half_rn(f);
    union { __half h; unsigned short s; } c; c.h = h; return c.s;
}
__device__ __forceinline__ __half2 u2h(unsigned u) {
    union { unsigned u; __half2 h; } c; c.u = u; return c.h;
}
__device__ __forceinline__ unsigned h2u(__half2 h) {
    union { __half2 h; unsigned u; } c; c.h = h; return c.u;
}
__device__ __forceinline__ __half2 shx(__half2 v, int m) {
    return u2h((unsigned)__shfl_xor((int)h2u(v), m, 64));
}
__device__ __forceinline__ ushort4 cvt4h(float4 v) {
    ushort4 o;
    o.x = f2h(v.x); o.y = f2h(v.y); o.z = f2h(v.z); o.w = f2h(v.w);
    return o;
}

// ---------------------------------------------------------------------------
// Fused prologue: convert 5 weight mats (contiguous dst), convert x, zero deg.
#define WSEG 18432
__global__ __launch_bounds__(256) void prologue_kernel(
    const float* __restrict__ W1l, const float* __restrict__ W1r,
    const float* __restrict__ W2l, const float* __restrict__ W2r,
    const float* __restrict__ W3,  const float* __restrict__ x,
    unsigned short* __restrict__ wb,   // 5 weight dsts contiguous
    unsigned short* __restrict__ xb,
    int* __restrict__ deg, int NX4, int ND4)
{
    int i = blockIdx.x * 256 + threadIdx.x;
    if (i < WSEG) {
        const float* s; int l;
        if (i < 8192)       { if (i < 4096) { s = W1l; l = i; }
                              else          { s = W1r; l = i - 4096; } }
        else if (i < 16384) { if (i < 12288){ s = W2l; l = i - 8192; }
                              else          { s = W2r; l = i - 12288; } }
        else                { s = W3; l = i - 16384; }
        ((ushort4*)wb)[i] = cvt4h(((const float4*)s)[l]);
        return;
    }
    int j = i - WSEG;
    if (j < NX4) { ((ushort4*)xb)[j] = cvt4h(((const float4*)x)[j]); return; }
    int k = j - NX4;
    if (k < ND4) ((int4*)deg)[k] = make_int4(0, 0, 0, 0);
}

// ---------------------------------------------------------------------------
// CSR build step 1: degree histogram over dst
__global__ __launch_bounds__(256) void hist_kernel(const int* __restrict__ dst,
                                                   int* __restrict__ deg, int E) {
    int e = blockIdx.x * 256 + threadIdx.x;
    if (e < E) atomicAdd(deg + dst[e], 1);
}

// CSR scan A: per-block sums (1024 elems/block)
__global__ __launch_bounds__(256) void scan_partial_kernel(
    const int* __restrict__ deg, int* __restrict__ partials, int N)
{
    __shared__ int ws[4];
    const int t = threadIdx.x, lane = t & 63, wave = t >> 6;
    const int i4 = blockIdx.x * 256 + t;
    const int n4 = (N + 3) / 4;
    int s = 0;
    if (i4 < n4) {
        int b = i4 * 4;
        if (b + 3 < N) {
            int4 v = ((const int4*)deg)[i4];
            s = v.x + v.y + v.z + v.w;
        } else {
            for (int q = 0; q < 4 && b + q < N; ++q) s += deg[b + q];
        }
    }
#pragma unroll
    for (int off = 32; off > 0; off >>= 1) s += __shfl_xor(s, off, 64);
    if (lane == 0) ws[wave] = s;
    __syncthreads();
    if (t == 0) partials[blockIdx.x] = ws[0] + ws[1] + ws[2] + ws[3];
}

// CSR scan B+C merged: each block redundantly reduces partials[< blockIdx]
// (P <= 64), re-scans its 1024 elems, writes rowptr & cursor.
__global__ __launch_bounds__(256) void scan_apply_kernel(
    const int* __restrict__ deg, const int* __restrict__ partials,
    int* __restrict__ rowptr, int* __restrict__ cursor, int N, int P)
{
    __shared__ int woff[4];
    __shared__ int s_base;
    const int t = threadIdx.x, lane = t & 63, wave = t >> 6;
    const int i4 = blockIdx.x * 256 + t;
    const int n4 = (N + 3) / 4;
    const int b = i4 * 4;

    if (wave == 0) {          // exclusive sum of block partials below us
        int v = (lane < P && lane < (int)blockIdx.x) ? partials[lane] : 0;
#pragma unroll
        for (int off = 32; off > 0; off >>= 1) v += __shfl_xor(v, off, 64);
        if (lane == 0) s_base = v;
    }

    int4 v = make_int4(0, 0, 0, 0);
    if (i4 < n4) {
        if (b + 3 < N) v = ((const int4*)deg)[i4];
        else {
            if (b + 0 < N) v.x = deg[b + 0];
            if (b + 1 < N) v.y = deg[b + 1];
            if (b + 2 < N) v.z = deg[b + 2];
        }
    }
    const int p1 = v.x, p2 = v.x + v.y, p3 = v.x + v.y + v.z;
    const int tsum = p3 + v.w;
    int incl = tsum;
#pragma unroll
    for (int off = 1; off < 64; off <<= 1) {
        int tt = __shfl_up(incl, off, 64);
        if (lane >= off) incl += tt;
    }
    const int texcl = incl - tsum;
    if (lane == 63) woff[wave] = incl;
    __syncthreads();
    int wo = 0;
#pragma unroll
    for (int w = 0; w < 4; ++w) if (w < wave) wo += woff[w];
    const int e = s_base + wo + texcl;
    if (blockIdx.x == 0 && t == 0) rowptr[0] = 0;
    if (b + 3 < N) {
        ((int4*)cursor)[i4] = make_int4(e, e + p1, e + p2, e + p3);
        rowptr[b + 1] = e + p1;
        rowptr[b + 2] = e + p2;
        rowptr[b + 3] = e + p3;
        rowptr[b + 4] = e + tsum;
    } else if (b < N) {
        if (b + 0 < N) { cursor[b + 0] = e;      rowptr[b + 1] = e + p1; }
        if (b + 1 < N) { cursor[b + 1] = e + p1; rowptr[b + 2] = e + p2; }
        if (b + 2 < N) { cursor[b + 2] = e + p2; rowptr[b + 3] = e + p3; }
    }
}

// CSR build: scatter src ids into neighbor lists
__global__ __launch_bounds__(256) void fill_kernel(const int* __restrict__ src,
                                                   const int* __restrict__ dst,
                                                   int* __restrict__ cursor,
                                                   int* __restrict__ csr, int E) {
    int e = blockIdx.x * 256 + threadIdx.x;
    if (e >= E) return;
    int pos = atomicAdd(cursor + dst[e], 1);
    csr[pos] = src[e];
}

// ---------------------------------------------------------------------------
// Fused SAGE layer: out = relu( mean(feat,nbrs) @ Wl^T + bias + feat @ Wr^T )
// One block per 16-row tile. Phase 1 (wave w -> nodes r0+4w..+3): lane =
// (nbr slot grp = lane>>4, col group = lane&15 covering 8 f16 cols / 16B).
// One dwordx4 wave-load fetches 4 neighbor rows; PACKED f16 accumulation
// (__hadd2 -> v_pk_add_f16, 1 op per 2 cols). OOB slots clamp+zero-mask
// (f16 0x0000 == 0.0). Node end: packed shfl_xor(16/32) cross-slot reduce,
// grp==0 lanes write f16 mean to LDS. Phase 2: wave w computes col-tiles
// {2w,2w+1} with mfma_f32_16x16x32_f16 (same fragment layout as bf16 —
// dtype-independent, m121/m123): A from LDS, self from global.
__global__ __launch_bounds__(256) void sage_layer_kernel(
    const unsigned short* __restrict__ feat,   // [N,128] f16 (gather + self)
    const int* __restrict__ rowptr, const int* __restrict__ csr,
    const unsigned short* __restrict__ Wl,
    const unsigned short* __restrict__ Wr,
    const float* __restrict__ bias,
    unsigned short* __restrict__ out,          // [N,128] f16
    int N)
{
    __shared__ unsigned short smean[16][136];
    const int wave = threadIdx.x >> 6;
    const int lane = threadIdx.x & 63;
    const int r0 = blockIdx.x * 16;

    // ---- phase 1: this wave gathers 4 of the block's 16 nodes ----
    {
        const int grp = lane >> 4;          // neighbor slot
        const int col = lane & 15;          // 8-col group (16B)
        const unsigned short* fq = feat + col * 8;
#pragma unroll
        for (int q = 0; q < 4; ++q) {
            const int mi = wave * 4 + q;
            const int n = r0 + mi;
            if (n >= N) break;
            const int beg = rowptr[n], end = rowptr[n + 1];
            const int deg = end - beg;
            __half2 c0 = u2h(0u), c1 = u2h(0u), c2 = u2h(0u), c3 = u2h(0u);
            // chunks of 4 neighbors per slot; 16 neighbors in flight
            for (int jA = beg + grp; jA < end; jA += 16) {
                const int jB = jA + 4, jC = jA + 8, jD = jA + 12;
                const unsigned mB = (jB < end) ? 0xffffffffu : 0u;
                const unsigned mC = (jC < end) ? 0xffffffffu : 0u;
                const unsigned mD = (jD < end) ? 0xffffffffu : 0u;
                const int iA = csr[jA];
                const int iB = csr[mB ? jB : beg];
                const int iC = csr[mC ? jC : beg];
                const int iD = csr[mD ? jD : beg];
                uint4 pA = *(const uint4*)(fq + (size_t)iA * 128);
                uint4 pB = *(const uint4*)(fq + (size_t)iB * 128);
                uint4 pC = *(const uint4*)(fq + (size_t)iC * 128);
                uint4 pD = *(const uint4*)(fq + (size_t)iD * 128);
                pB.x &= mB; pB.y &= mB; pB.z &= mB; pB.w &= mB;
                pC.x &= mC; pC.y &= mC; pC.z &= mC; pC.w &= mC;
                pD.x &= mD; pD.y &= mD; pD.z &= mD; pD.w &= mD;
                c0 = __hadd2(c0, u2h(pA.x)); c1 = __hadd2(c1, u2h(pA.y));
                c2 = __hadd2(c2, u2h(pA.z)); c3 = __hadd2(c3, u2h(pA.w));
                c0 = __hadd2(c0, u2h(pB.x)); c1 = __hadd2(c1, u2h(pB.y));
                c2 = __hadd2(c2, u2h(pB.z)); c3 = __hadd2(c3, u2h(pB.w));
                c0 = __hadd2(c0, u2h(pC.x)); c1 = __hadd2(c1, u2h(pC.y));
                c2 = __hadd2(c2, u2h(pC.z)); c3 = __hadd2(c3, u2h(pC.w));
                c0 = __hadd2(c0, u2h(pD.x)); c1 = __hadd2(c1, u2h(pD.y));
                c2 = __hadd2(c2, u2h(pD.z)); c3 = __hadd2(c3, u2h(pD.w));
            }
            // packed cross-slot reduce (slots live in lane bits 4,5)
            c0 = __hadd2(c0, shx(c0, 16)); c0 = __hadd2(c0, shx(c0, 32));
            c1 = __hadd2(c1, shx(c1, 16)); c1 = __hadd2(c1, shx(c1, 32));
            c2 = __hadd2(c2, shx(c2, 16)); c2 = __hadd2(c2, shx(c2, 32));
            c3 = __hadd2(c3, shx(c3, 16)); c3 = __hadd2(c3, shx(c3, 32));
            if (grp == 0) {
                const float inv = (deg > 0) ? 1.0f / (float)deg : 0.0f;
                uint4 o;
                o.x = h2u(__floats2half2_rn(__low2float(c0) * inv,
                                            __high2float(c0) * inv));
                o.y = h2u(__floats2half2_rn(__low2float(c1) * inv,
                                            __high2float(c1) * inv));
                o.z = h2u(__floats2half2_rn(__low2float(c2) * inv,
                                            __high2float(c2) * inv));
                o.w = h2u(__floats2half2_rn(__low2float(c3) * inv,
                                            __high2float(c3) * inv));
                *(uint4*)&smean[mi][col * 8] = o;
            }
        }
    }
    __syncthreads();

    // ---- phase 2: this wave computes col-tiles 2*wave, 2*wave+1 ----
    const int mrow = lane & 15;
    const int quad = lane >> 4;
    int selfRow = r0 + mrow;
    if (selfRow >= N) selfRow = N - 1;      // partial-tile clamp (loads only)
    const size_t rowS = (size_t)selfRow * 128;

    floatx4 acc0 = (floatx4)(0.0f), acc1 = (floatx4)(0.0f);
    const int t0 = wave * 2, t1 = wave * 2 + 1;

#pragma unroll
    for (int kk = 0; kk < 4; ++kk) {
        const int k = kk * 32 + quad * 8;
        f16x8 aA = *(const f16x8*)&smean[mrow][k];
        f16x8 aS = *(const f16x8*)(feat + rowS + k);
        f16x8 bl0 = *(const f16x8*)(Wl + (size_t)(t0 * 16 + mrow) * 128 + k);
        acc0 = __builtin_amdgcn_mfma_f32_16x16x32_f16(aA, bl0, acc0, 0, 0, 0);
        f16x8 br0 = *(const f16x8*)(Wr + (size_t)(t0 * 16 + mrow) * 128 + k);
        acc0 = __builtin_amdgcn_mfma_f32_16x16x32_f16(aS, br0, acc0, 0, 0, 0);
        f16x8 bl1 = *(const f16x8*)(Wl + (size_t)(t1 * 16 + mrow) * 128 + k);
        acc1 = __builtin_amdgcn_mfma_f32_16x16x32_f16(aA, bl1, acc1, 0, 0, 0);
        f16x8 br1 = *(const f16x8*)(Wr + (size_t)(t1 * 16 + mrow) * 128 + k);
        acc1 = __builtin_amdgcn_mfma_f32_16x16x32_f16(aS, br1, acc1, 0, 0, 0);
    }

    const float b0 = bias[t0 * 16 + mrow];
    const float b1 = bias[t1 * 16 + mrow];
#pragma unroll
    for (int i = 0; i < 4; ++i) {
        const int r = r0 + quad * 4 + i;
        if (r < N) {
            out[(size_t)r * 128 + t0 * 16 + mrow] = f2h(fmaxf(acc0[i] + b0, 0.0f));
            out[(size_t)r * 128 + t1 * 16 + mrow] = f2h(fmaxf(acc1[i] + b1, 0.0f));
        }
    }
}

// ---------------------------------------------------------------------------
// Head GEMM: out = inA @ W3^T + b3  (fp32 out, 64 cols)
__global__ __launch_bounds__(256) void head_gemm_kernel(
    const unsigned short* __restrict__ inA,
    const unsigned short* __restrict__ W,
    const float* __restrict__ bias,
    float* __restrict__ out,
    int M)
{
    const int wave = threadIdx.x >> 6;
    const int lane = threadIdx.x & 63;
    const int r0 = (blockIdx.x * 4 + wave) * 16;
    if (r0 >= M) return;
    const int mrow = lane & 15;
    const int quad = lane >> 4;
    const size_t rowA = (size_t)(r0 + mrow) * 128;

    floatx4 acc[4];
#pragma unroll
    for (int t = 0; t < 4; ++t) acc[t] = (floatx4)(0.0f);

#pragma unroll
    for (int kk = 0; kk < 4; ++kk) {
        const int k = kk * 32 + quad * 8;
        f16x8 aA = *(const f16x8*)(inA + rowA + k);
#pragma unroll
        for (int t = 0; t < 4; ++t) {
            f16x8 b = *(const f16x8*)(W + (size_t)(t * 16 + mrow) * 128 + k);
            acc[t] = __builtin_amdgcn_mfma_f32_16x16x32_f16(aA, b, acc[t], 0, 0, 0);
        }
    }

#pragma unroll
    for (int t = 0; t < 4; ++t) {
        float b = bias[t * 16 + mrow];
#pragma unroll
        for (int i = 0; i < 4; ++i)
            out[(size_t)(r0 + quad * 4 + i) * 64 + t * 16 + mrow] = acc[t][i] + b;
    }
}

// ---------------------------------------------------------------------------
extern "C" void kernel_launch(void* const* d_in, const int* in_sizes, int n_in,
                              void* d_out, int out_size, void* d_ws, size_t ws_size,
                              hipStream_t stream)
{
    const float* x   = (const float*)d_in[0];
    const int* ei    = (const int*)d_in[1];
    const float* W1l = (const float*)d_in[2];
    const float* b1l = (const float*)d_in[3];
    const float* W1r = (const float*)d_in[4];
    const float* W2l = (const float*)d_in[5];
    const float* b2l = (const float*)d_in[6];
    const float* W2r = (const float*)d_in[7];
    const float* W3  = (const float*)d_in[8];
    const float* b3  = (const float*)d_in[9];
    float* out = (float*)d_out;

    const int N = in_sizes[0] / 128;   // 50000
    const int E = in_sizes[1] / 2;     // 640000
    const int* src = ei;
    const int* dst = ei + E;

    // workspace layout (all offsets 16B aligned):
    //   deg_i : N ints (pad x4)  partials: 64 ints
    //   rowptr: N+4 ints         cursor  : N ints
    //   csr   : E ints           xb/h1/h2: N*128 f16 each
    //   wb    : 5 f16 weight mats contiguous
    const int n4 = (N + 3) / 4;
    int* deg_i    = (int*)d_ws;
    int* partials = deg_i + n4 * 4;
    int* rowptr   = partials + 64;
    int* cursor   = rowptr + N + 4;
    int* csr      = cursor + n4 * 4;
    unsigned short* xb   = (unsigned short*)(csr + E);
    unsigned short* h1   = xb + (size_t)N * 128;
    unsigned short* h2   = h1 + (size_t)N * 128;
    unsigned short* wb1l = h2 + (size_t)N * 128;
    unsigned short* wb1r = wb1l + 16384;
    unsigned short* wb2l = wb1r + 16384;
    unsigned short* wb2r = wb2l + 16384;
    unsigned short* wb3  = wb2r + 16384;

    const int lblk = (N + 15) / 16;             // fused layer: 1 tile/block
    const int gblk = ((N + 15) / 16 + 3) / 4;   // head: 4 tiles/block
    const int eblk = (E + 255) / 256;
    const int NX4  = N * 32;                    // x in float4 units
    const int P    = (n4 + 255) / 256;          // scan blocks (<=64 for N<=65536)

    // ---- fused prologue: weight cvt + x cvt + deg zero (1 launch) ----
    {
        int total = WSEG + NX4 + n4;
        hipLaunchKernelGGL(prologue_kernel, dim3((total + 255) / 256), dim3(256), 0,
                           stream, W1l, W1r, W2l, W2r, W3, x, wb1l, xb, deg_i,
                           NX4, n4);
    }

    // ---- CSR build (once; reused by both layers) ----
    hipLaunchKernelGGL(hist_kernel, dim3(eblk), dim3(256), 0, stream, dst, deg_i, E);
    hipLaunchKernelGGL(scan_partial_kernel, dim3(P), dim3(256), 0, stream,
                       deg_i, partials, N);
    hipLaunchKernelGGL(scan_apply_kernel, dim3(P), dim3(256), 0, stream,
                       deg_i, partials, rowptr, cursor, N, P);
    hipLaunchKernelGGL(fill_kernel, dim3(eblk), dim3(256), 0, stream,
                       src, dst, cursor, csr, E);

    // ---- fused layers ----
    hipLaunchKernelGGL(sage_layer_kernel, dim3(lblk), dim3(256), 0, stream,
                       xb, rowptr, csr, wb1l, wb1r, b1l, h1, N);
    hipLaunchKernelGGL(sage_layer_kernel, dim3(lblk), dim3(256), 0, stream,
                       h1, rowptr, csr, wb2l, wb2r, b2l, h2, N);
    // ---- output head ----
    hipLaunchKernelGGL(head_gemm_kernel, dim3(gblk), dim3(256), 0, stream,
                       h2, wb3, b3, out, N);
}

// Round 10
// 267.058 us; speedup vs baseline: 1.2037x; 1.0551x over previous
//
#include <hip/hip_runtime.h>
#include <hip/hip_fp16.h>

// ---------------------------------------------------------------------------
// GNN_6305011991202: 2-layer GraphSAGE (mean aggr) + linear head. fp32 I/O.
//   h1 = relu(mean1 @ W1_l^T + b1_l + x  @ W1_r^T)
//   h2 = relu(mean2 @ W2_l^T + b2_l + h1 @ W2_r^T)
//   out = h2 @ W3^T + b3          (out: [50000, 64] fp32)
// R10: fp8(e4m3) feature table for the GATHER path (row = 128 B = 1 cache
// line): halves random-gather bytes+line-requests; 6.4 MB table ~fits per-XCD
// L2 (was 12.8 vs 4 MB -> compulsory 8x replication dominated FETCH=92MB).
// Self path, GEMMs, stored h stay f16. HW cvt_pk_f32_fp8 + v_pk_add_f32.
// ---------------------------------------------------------------------------

typedef _Float16 f16x8 __attribute__((ext_vector_type(8)));
typedef float floatx4 __attribute__((ext_vector_type(4)));
typedef float floatx2 __attribute__((ext_vector_type(2)));

__device__ __forceinline__ unsigned short f2h(float f) {
    __half h = __float2half_rn(f);
    union { __half h; unsigned short s; } c; c.h = h; return c.s;
}
__device__ __forceinline__ __half2 u2h(unsigned u) {
    union { unsigned u; __half2 h; } c; c.u = u; return c.h;
}
__device__ __forceinline__ unsigned h2u(__half2 h) {
    union { __half2 h; unsigned u; } c; c.h = h; return c.u;
}
__device__ __forceinline__ __half2 shx(__half2 v, int m) {
    return u2h((unsigned)__shfl_xor((int)h2u(v), m, 64));
}
__device__ __forceinline__ ushort4 cvt4h(float4 v) {
    ushort4 o;
    o.x = f2h(v.x); o.y = f2h(v.y); o.z = f2h(v.z); o.w = f2h(v.w);
    return o;
}
__device__ __forceinline__ unsigned char f2fp8(float v) {
    return (unsigned char)(__builtin_amdgcn_cvt_pk_fp8_f32(v, v, 0, false) & 0xff);
}

// ---------------------------------------------------------------------------
// Fused prologue: convert 5 weight mats (f16, contiguous dst), x -> f16 AND
// fp8 tables, zero deg.
#define WSEG 18432
__global__ __launch_bounds__(256) void prologue_kernel(
    const float* __restrict__ W1l, const float* __restrict__ W1r,
    const float* __restrict__ W2l, const float* __restrict__ W2r,
    const float* __restrict__ W3,  const float* __restrict__ x,
    unsigned short* __restrict__ wb,   // 5 weight dsts contiguous
    unsigned short* __restrict__ xb,
    unsigned char* __restrict__ x8,
    int* __restrict__ deg, int NX4, int ND4)
{
    int i = blockIdx.x * 256 + threadIdx.x;
    if (i < WSEG) {
        const float* s; int l;
        if (i < 8192)       { if (i < 4096) { s = W1l; l = i; }
                              else          { s = W1r; l = i - 4096; } }
        else if (i < 16384) { if (i < 12288){ s = W2l; l = i - 8192; }
                              else          { s = W2r; l = i - 12288; } }
        else                { s = W3; l = i - 16384; }
        ((ushort4*)wb)[i] = cvt4h(((const float4*)s)[l]);
        return;
    }
    int j = i - WSEG;
    if (j < NX4) {
        float4 v = ((const float4*)x)[j];
        ((ushort4*)xb)[j] = cvt4h(v);
        unsigned u8 = __builtin_amdgcn_cvt_pk_fp8_f32(v.x, v.y, 0, false);
        u8 = __builtin_amdgcn_cvt_pk_fp8_f32(v.z, v.w, u8, true);
        ((unsigned*)x8)[j] = u8;
        return;
    }
    int k = j - NX4;
    if (k < ND4) ((int4*)deg)[k] = make_int4(0, 0, 0, 0);
}

// ---------------------------------------------------------------------------
// CSR build step 1: degree histogram over dst
__global__ __launch_bounds__(256) void hist_kernel(const int* __restrict__ dst,
                                                   int* __restrict__ deg, int E) {
    int e = blockIdx.x * 256 + threadIdx.x;
    if (e < E) atomicAdd(deg + dst[e], 1);
}

// CSR scan A: per-block sums (1024 elems/block)
__global__ __launch_bounds__(256) void scan_partial_kernel(
    const int* __restrict__ deg, int* __restrict__ partials, int N)
{
    __shared__ int ws[4];
    const int t = threadIdx.x, lane = t & 63, wave = t >> 6;
    const int i4 = blockIdx.x * 256 + t;
    const int n4 = (N + 3) / 4;
    int s = 0;
    if (i4 < n4) {
        int b = i4 * 4;
        if (b + 3 < N) {
            int4 v = ((const int4*)deg)[i4];
            s = v.x + v.y + v.z + v.w;
        } else {
            for (int q = 0; q < 4 && b + q < N; ++q) s += deg[b + q];
        }
    }
#pragma unroll
    for (int off = 32; off > 0; off >>= 1) s += __shfl_xor(s, off, 64);
    if (lane == 0) ws[wave] = s;
    __syncthreads();
    if (t == 0) partials[blockIdx.x] = ws[0] + ws[1] + ws[2] + ws[3];
}

// CSR scan B+C merged: each block redundantly reduces partials[< blockIdx]
// (P <= 64), re-scans its 1024 elems, writes rowptr & cursor.
__global__ __launch_bounds__(256) void scan_apply_kernel(
    const int* __restrict__ deg, const int* __restrict__ partials,
    int* __restrict__ rowptr, int* __restrict__ cursor, int N, int P)
{
    __shared__ int woff[4];
    __shared__ int s_base;
    const int t = threadIdx.x, lane = t & 63, wave = t >> 6;
    const int i4 = blockIdx.x * 256 + t;
    const int n4 = (N + 3) / 4;
    const int b = i4 * 4;

    if (wave == 0) {          // exclusive sum of block partials below us
        int v = (lane < P && lane < (int)blockIdx.x) ? partials[lane] : 0;
#pragma unroll
        for (int off = 32; off > 0; off >>= 1) v += __shfl_xor(v, off, 64);
        if (lane == 0) s_base = v;
    }

    int4 v = make_int4(0, 0, 0, 0);
    if (i4 < n4) {
        if (b + 3 < N) v = ((const int4*)deg)[i4];
        else {
            if (b + 0 < N) v.x = deg[b + 0];
            if (b + 1 < N) v.y = deg[b + 1];
            if (b + 2 < N) v.z = deg[b + 2];
        }
    }
    const int p1 = v.x, p2 = v.x + v.y, p3 = v.x + v.y + v.z;
    const int tsum = p3 + v.w;
    int incl = tsum;
#pragma unroll
    for (int off = 1; off < 64; off <<= 1) {
        int tt = __shfl_up(incl, off, 64);
        if (lane >= off) incl += tt;
    }
    const int texcl = incl - tsum;
    if (lane == 63) woff[wave] = incl;
    __syncthreads();
    int wo = 0;
#pragma unroll
    for (int w = 0; w < 4; ++w) if (w < wave) wo += woff[w];
    const int e = s_base + wo + texcl;
    if (blockIdx.x == 0 && t == 0) rowptr[0] = 0;
    if (b + 3 < N) {
        ((int4*)cursor)[i4] = make_int4(e, e + p1, e + p2, e + p3);
        rowptr[b + 1] = e + p1;
        rowptr[b + 2] = e + p2;
        rowptr[b + 3] = e + p3;
        rowptr[b + 4] = e + tsum;
    } else if (b < N) {
        if (b + 0 < N) { cursor[b + 0] = e;      rowptr[b + 1] = e + p1; }
        if (b + 1 < N) { cursor[b + 1] = e + p1; rowptr[b + 2] = e + p2; }
        if (b + 2 < N) { cursor[b + 2] = e + p2; rowptr[b + 3] = e + p3; }
    }
}

// CSR build: scatter src ids into neighbor lists
__global__ __launch_bounds__(256) void fill_kernel(const int* __restrict__ src,
                                                   const int* __restrict__ dst,
                                                   int* __restrict__ cursor,
                                                   int* __restrict__ csr, int E) {
    int e = blockIdx.x * 256 + threadIdx.x;
    if (e >= E) return;
    int pos = atomicAdd(cursor + dst[e], 1);
    csr[pos] = src[e];
}

// ---------------------------------------------------------------------------
// Fused SAGE layer: out = relu( mean(feat8,nbrs) @ Wl^T + bias + feat @ Wr^T )
// One block per 16-row tile. Phase 1 (wave w -> nodes r0+4w..+3): lane =
// (nbr slot grp = lane>>4, col group = lane&15 covering 8 fp8 cols / 8B).
// One dwordx2 wave-load fetches 4 neighbor fp8 rows (128B = 1 line each);
// HW cvt_pk_f32_fp8 unpack + v_pk_add_f32 accumulate. OOB slots clamp +
// zero-mask (fp8 0x00 == 0.0). Node end: pack to f16, packed shfl_xor(16/32)
// cross-slot reduce, grp==0 lanes write f16 mean to LDS. Phase 2: wave w
// computes col-tiles {2w,2w+1} with mfma_f32_16x16x32_f16 (A from LDS, self
// f16 from global); WFP8 additionally stores an fp8 copy of out (next layer's
// gather table).
template <bool WFP8>
__global__ __launch_bounds__(256) void sage_layer_kernel(
    const unsigned short* __restrict__ feat,   // [N,128] f16 (self path)
    const unsigned char* __restrict__ feat8,   // [N,128] fp8 (gather path)
    const int* __restrict__ rowptr, const int* __restrict__ csr,
    const unsigned short* __restrict__ Wl,
    const unsigned short* __restrict__ Wr,
    const float* __restrict__ bias,
    unsigned short* __restrict__ out,          // [N,128] f16
    unsigned char* __restrict__ out8,          // [N,128] fp8 (if WFP8)
    int N)
{
    __shared__ unsigned short smean[16][136];
    const int wave = threadIdx.x >> 6;
    const int lane = threadIdx.x & 63;
    const int r0 = blockIdx.x * 16;

    // ---- phase 1: this wave gathers 4 of the block's 16 nodes ----
    {
        const int grp = lane >> 4;          // neighbor slot
        const int col = lane & 15;          // 8-col group (8B of fp8)
        const unsigned char* fq = feat8 + col * 8;
#pragma unroll
        for (int q = 0; q < 4; ++q) {
            const int mi = wave * 4 + q;
            const int n = r0 + mi;
            if (n >= N) break;
            const int beg = rowptr[n], end = rowptr[n + 1];
            const int deg = end - beg;
            floatx2 a0 = (floatx2)(0.f), a1 = (floatx2)(0.f);
            floatx2 a2 = (floatx2)(0.f), a3 = (floatx2)(0.f);
            // chunks of 4 neighbors per slot; 16 neighbors in flight
            for (int jA = beg + grp; jA < end; jA += 16) {
                const int jB = jA + 4, jC = jA + 8, jD = jA + 12;
                const unsigned mB = (jB < end) ? 0xffffffffu : 0u;
                const unsigned mC = (jC < end) ? 0xffffffffu : 0u;
                const unsigned mD = (jD < end) ? 0xffffffffu : 0u;
                const int iA = csr[jA];
                const int iB = csr[mB ? jB : beg];
                const int iC = csr[mC ? jC : beg];
                const int iD = csr[mD ? jD : beg];
                uint2 pA = *(const uint2*)(fq + (size_t)iA * 128);
                uint2 pB = *(const uint2*)(fq + (size_t)iB * 128);
                uint2 pC = *(const uint2*)(fq + (size_t)iC * 128);
                uint2 pD = *(const uint2*)(fq + (size_t)iD * 128);
                pB.x &= mB; pB.y &= mB;
                pC.x &= mC; pC.y &= mC;
                pD.x &= mD; pD.y &= mD;
                a0 += __builtin_amdgcn_cvt_pk_f32_fp8(pA.x, false);
                a1 += __builtin_amdgcn_cvt_pk_f32_fp8(pA.x, true);
                a2 += __builtin_amdgcn_cvt_pk_f32_fp8(pA.y, false);
                a3 += __builtin_amdgcn_cvt_pk_f32_fp8(pA.y, true);
                a0 += __builtin_amdgcn_cvt_pk_f32_fp8(pB.x, false);
                a1 += __builtin_amdgcn_cvt_pk_f32_fp8(pB.x, true);
                a2 += __builtin_amdgcn_cvt_pk_f32_fp8(pB.y, false);
                a3 += __builtin_amdgcn_cvt_pk_f32_fp8(pB.y, true);
                a0 += __builtin_amdgcn_cvt_pk_f32_fp8(pC.x, false);
                a1 += __builtin_amdgcn_cvt_pk_f32_fp8(pC.x, true);
                a2 += __builtin_amdgcn_cvt_pk_f32_fp8(pC.y, false);
                a3 += __builtin_amdgcn_cvt_pk_f32_fp8(pC.y, true);
                a0 += __builtin_amdgcn_cvt_pk_f32_fp8(pD.x, false);
                a1 += __builtin_amdgcn_cvt_pk_f32_fp8(pD.x, true);
                a2 += __builtin_amdgcn_cvt_pk_f32_fp8(pD.y, false);
                a3 += __builtin_amdgcn_cvt_pk_f32_fp8(pD.y, true);
            }
            // pack partial f32 sums -> f16 pairs, packed cross-slot reduce
            __half2 c0 = __floats2half2_rn(a0.x, a0.y);
            __half2 c1 = __floats2half2_rn(a1.x, a1.y);
            __half2 c2 = __floats2half2_rn(a2.x, a2.y);
            __half2 c3 = __floats2half2_rn(a3.x, a3.y);
            c0 = __hadd2(c0, shx(c0, 16)); c0 = __hadd2(c0, shx(c0, 32));
            c1 = __hadd2(c1, shx(c1, 16)); c1 = __hadd2(c1, shx(c1, 32));
            c2 = __hadd2(c2, shx(c2, 16)); c2 = __hadd2(c2, shx(c2, 32));
            c3 = __hadd2(c3, shx(c3, 16)); c3 = __hadd2(c3, shx(c3, 32));
            if (grp == 0) {
                const float inv = (deg > 0) ? 1.0f / (float)deg : 0.0f;
                uint4 o;
                o.x = h2u(__floats2half2_rn(__low2float(c0) * inv,
                                            __high2float(c0) * inv));
                o.y = h2u(__floats2half2_rn(__low2float(c1) * inv,
                                            __high2float(c1) * inv));
                o.z = h2u(__floats2half2_rn(__low2float(c2) * inv,
                                            __high2float(c2) * inv));
                o.w = h2u(__floats2half2_rn(__low2float(c3) * inv,
                                            __high2float(c3) * inv));
                *(uint4*)&smean[mi][col * 8] = o;
            }
        }
    }
    __syncthreads();

    // ---- phase 2: this wave computes col-tiles 2*wave, 2*wave+1 ----
    const int mrow = lane & 15;
    const int quad = lane >> 4;
    int selfRow = r0 + mrow;
    if (selfRow >= N) selfRow = N - 1;      // partial-tile clamp (loads only)
    const size_t rowS = (size_t)selfRow * 128;

    floatx4 acc0 = (floatx4)(0.0f), acc1 = (floatx4)(0.0f);
    const int t0 = wave * 2, t1 = wave * 2 + 1;

#pragma unroll
    for (int kk = 0; kk < 4; ++kk) {
        const int k = kk * 32 + quad * 8;
        f16x8 aA = *(const f16x8*)&smean[mrow][k];
        f16x8 aS = *(const f16x8*)(feat + rowS + k);
        f16x8 bl0 = *(const f16x8*)(Wl + (size_t)(t0 * 16 + mrow) * 128 + k);
        acc0 = __builtin_amdgcn_mfma_f32_16x16x32_f16(aA, bl0, acc0, 0, 0, 0);
        f16x8 br0 = *(const f16x8*)(Wr + (size_t)(t0 * 16 + mrow) * 128 + k);
        acc0 = __builtin_amdgcn_mfma_f32_16x16x32_f16(aS, br0, acc0, 0, 0, 0);
        f16x8 bl1 = *(const f16x8*)(Wl + (size_t)(t1 * 16 + mrow) * 128 + k);
        acc1 = __builtin_amdgcn_mfma_f32_16x16x32_f16(aA, bl1, acc1, 0, 0, 0);
        f16x8 br1 = *(const f16x8*)(Wr + (size_t)(t1 * 16 + mrow) * 128 + k);
        acc1 = __builtin_amdgcn_mfma_f32_16x16x32_f16(aS, br1, acc1, 0, 0, 0);
    }

    const float b0 = bias[t0 * 16 + mrow];
    const float b1 = bias[t1 * 16 + mrow];
#pragma unroll
    for (int i = 0; i < 4; ++i) {
        const int r = r0 + quad * 4 + i;
        if (r < N) {
            float v0 = fmaxf(acc0[i] + b0, 0.0f);
            float v1 = fmaxf(acc1[i] + b1, 0.0f);
            out[(size_t)r * 128 + t0 * 16 + mrow] = f2h(v0);
            out[(size_t)r * 128 + t1 * 16 + mrow] = f2h(v1);
            if (WFP8) {
                out8[(size_t)r * 128 + t0 * 16 + mrow] = f2fp8(v0);
                out8[(size_t)r * 128 + t1 * 16 + mrow] = f2fp8(v1);
            }
        }
    }
}

// ---------------------------------------------------------------------------
// Head GEMM: out = inA @ W3^T + b3  (fp32 out, 64 cols)
__global__ __launch_bounds__(256) void head_gemm_kernel(
    const unsigned short* __restrict__ inA,
    const unsigned short* __restrict__ W,
    const float* __restrict__ bias,
    float* __restrict__ out,
    int M)
{
    const int wave = threadIdx.x >> 6;
    const int lane = threadIdx.x & 63;
    const int r0 = (blockIdx.x * 4 + wave) * 16;
    if (r0 >= M) return;
    const int mrow = lane & 15;
    const int quad = lane >> 4;
    const size_t rowA = (size_t)(r0 + mrow) * 128;

    floatx4 acc[4];
#pragma unroll
    for (int t = 0; t < 4; ++t) acc[t] = (floatx4)(0.0f);

#pragma unroll
    for (int kk = 0; kk < 4; ++kk) {
        const int k = kk * 32 + quad * 8;
        f16x8 aA = *(const f16x8*)(inA + rowA + k);
#pragma unroll
        for (int t = 0; t < 4; ++t) {
            f16x8 b = *(const f16x8*)(W + (size_t)(t * 16 + mrow) * 128 + k);
            acc[t] = __builtin_amdgcn_mfma_f32_16x16x32_f16(aA, b, acc[t], 0, 0, 0);
        }
    }

#pragma unroll
    for (int t = 0; t < 4; ++t) {
        float b = bias[t * 16 + mrow];
#pragma unroll
        for (int i = 0; i < 4; ++i)
            out[(size_t)(r0 + quad * 4 + i) * 64 + t * 16 + mrow] = acc[t][i] + b;
    }
}

// ---------------------------------------------------------------------------
extern "C" void kernel_launch(void* const* d_in, const int* in_sizes, int n_in,
                              void* d_out, int out_size, void* d_ws, size_t ws_size,
                              hipStream_t stream)
{
    const float* x   = (const float*)d_in[0];
    const int* ei    = (const int*)d_in[1];
    const float* W1l = (const float*)d_in[2];
    const float* b1l = (const float*)d_in[3];
    const float* W1r = (const float*)d_in[4];
    const float* W2l = (const float*)d_in[5];
    const float* b2l = (const float*)d_in[6];
    const float* W2r = (const float*)d_in[7];
    const float* W3  = (const float*)d_in[8];
    const float* b3  = (const float*)d_in[9];
    float* out = (float*)d_out;

    const int N = in_sizes[0] / 128;   // 50000
    const int E = in_sizes[1] / 2;     // 640000
    const int* src = ei;
    const int* dst = ei + E;

    // workspace layout (all offsets 16B aligned):
    //   deg_i : n4*4 ints        partials: 64 ints
    //   rowptr: N+4 ints         cursor  : n4*4 ints
    //   csr   : E ints           xb/h1/h2: N*128 f16 each
    //   wb    : 5 f16 weight mats contiguous
    //   x8/h18: N*128 fp8 each (gather tables)
    const int n4 = (N + 3) / 4;
    int* deg_i    = (int*)d_ws;
    int* partials = deg_i + n4 * 4;
    int* rowptr   = partials + 64;
    int* cursor   = rowptr + N + 4;
    int* csr      = cursor + n4 * 4;
    unsigned short* xb   = (unsigned short*)(csr + E);
    unsigned short* h1   = xb + (size_t)N * 128;
    unsigned short* h2   = h1 + (size_t)N * 128;
    unsigned short* wb1l = h2 + (size_t)N * 128;
    unsigned short* wb1r = wb1l + 16384;
    unsigned short* wb2l = wb1r + 16384;
    unsigned short* wb2r = wb2l + 16384;
    unsigned short* wb3  = wb2r + 16384;
    unsigned char* x8    = (unsigned char*)(wb3 + 8192);
    unsigned char* h18   = x8 + (size_t)N * 128;

    const int lblk = (N + 15) / 16;             // fused layer: 1 tile/block
    const int gblk = ((N + 15) / 16 + 3) / 4;   // head: 4 tiles/block
    const int eblk = (E + 255) / 256;
    const int NX4  = N * 32;                    // x in float4 units
    const int P    = (n4 + 255) / 256;          // scan blocks (<=64 for N<=65536)

    // ---- fused prologue: weight cvt + x cvt (f16+fp8) + deg zero ----
    {
        int total = WSEG + NX4 + n4;
        hipLaunchKernelGGL(prologue_kernel, dim3((total + 255) / 256), dim3(256), 0,
                           stream, W1l, W1r, W2l, W2r, W3, x, wb1l, xb, x8, deg_i,
                           NX4, n4);
    }

    // ---- CSR build (once; reused by both layers) ----
    hipLaunchKernelGGL(hist_kernel, dim3(eblk), dim3(256), 0, stream, dst, deg_i, E);
    hipLaunchKernelGGL(scan_partial_kernel, dim3(P), dim3(256), 0, stream,
                       deg_i, partials, N);
    hipLaunchKernelGGL(scan_apply_kernel, dim3(P), dim3(256), 0, stream,
                       deg_i, partials, rowptr, cursor, N, P);
    hipLaunchKernelGGL(fill_kernel, dim3(eblk), dim3(256), 0, stream,
                       src, dst, cursor, csr, E);

    // ---- fused layers ----
    hipLaunchKernelGGL((sage_layer_kernel<true>), dim3(lblk), dim3(256), 0, stream,
                       xb, x8, rowptr, csr, wb1l, wb1r, b1l, h1, h18, N);
    hipLaunchKernelGGL((sage_layer_kernel<false>), dim3(lblk), dim3(256), 0, stream,
                       h1, h18, rowptr, csr, wb2l, wb2r, b2l, h2, nullptr, N);
    // ---- output head ----
    hipLaunchKernelGGL(head_gemm_kernel, dim3(gblk), dim3(256), 0, stream,
                       h2, wb3, b3, out, N);
}